// Round 9
// baseline (322.464 us; speedup 1.0000x reference)
//
#include <hip/hip_runtime.h>
#include <hip/hip_bf16.h>

#define SPAN_SHIFT 8   // dst-bucket span = 256 nodes

typedef __attribute__((ext_vector_type(8))) short short8;
typedef __attribute__((ext_vector_type(4))) float float4v;

// ---------- bf16 helpers (OCP bf16 = fp32 upper 16 bits) ----------
__device__ __forceinline__ float bf2f(unsigned short u) {
  union { unsigned int i; float f; } v; v.i = ((unsigned int)u) << 16; return v.f;
}
__device__ __forceinline__ unsigned short f2bf(float f) {
  union { float f; unsigned int i; } v; v.f = f;
  unsigned int x = v.i;
  return (unsigned short)((x + 0x7fffu + ((x >> 16) & 1u)) >> 16);  // RNE
}

// ---------- 0. per-tensor runtime dtype detection ----------
// flags[0]=x_fp32 flags[1]=int64 flags[2]=w1_fp32 flags[3]=w2_fp32 flags[4]=b1_fp32 flags[5]=b2_fp32
__global__ __launch_bounds__(256) void detect_all_k(
    const unsigned short* __restrict__ xu,  const int* __restrict__ ei,
    const unsigned short* __restrict__ w1u, const unsigned short* __restrict__ w2u,
    const unsigned short* __restrict__ b1u, const unsigned short* __restrict__ b2u,
    int* __restrict__ flags) {
  __shared__ int s_cnt;
  if (threadIdx.x == 0) s_cnt = 0;
  __syncthreads();
  const int b = blockIdx.x;
  int cnt = 0;
  if (b == 1) {  // int width: high words of int64 positives are all zero
    for (int i = threadIdx.x; i < 4096; i += 256)
      if (ei[2 * i + 1] == 0) cnt++;
    atomicAdd(&s_cnt, cnt);
    __syncthreads();
    if (threadIdx.x == 0) flags[1] = (s_cnt > 2048) ? 1 : 0;
    return;
  }
  const unsigned short* p; int n; int fi;
  if (b == 0)      { p = xu;  n = 16384; fi = 0; }
  else if (b == 2) { p = w1u; n = 16384; fi = 2; }
  else if (b == 3) { p = w2u; n = 16384; fi = 3; }
  else if (b == 4) { p = b1u; n = 128;   fi = 4; }
  else             { p = b2u; n = 128;   fi = 5; }
  for (int i = threadIdx.x; i < n; i += 256) {
    int e = (p[i] >> 7) & 0xFF;
    if (e < 96 || e > 159) cnt++;   // wild bf16 exponent => fp32 data
  }
  atomicAdd(&s_cnt, cnt);
  __syncthreads();
  if (threadIdx.x == 0) flags[fi] = (s_cnt * 8 > n) ? 1 : 0;
}

// ---------- 1. degree count ----------
__global__ void count_deg_k(const int* __restrict__ ei, int* __restrict__ deg, int E,
                            const int* __restrict__ flags) {
  int e = blockIdx.x * blockDim.x + threadIdx.x;
  if (e >= E) return;
  int d = flags[1] ? ei[2 * (E + e)] : ei[E + e];
  atomicAdd(&deg[d], 1);
}

// ---------- 2. hierarchical exclusive scan ----------
__global__ __launch_bounds__(256) void scan1_k(const int* __restrict__ deg,
                                               int* __restrict__ bsum, int N) {
  __shared__ int red[4];
  int i = blockIdx.x * 256 + threadIdx.x;
  int v = (i < N) ? deg[i] : 0;
  int lane = threadIdx.x & 63, w = threadIdx.x >> 6;
  #pragma unroll
  for (int off = 32; off > 0; off >>= 1) v += __shfl_down(v, off, 64);
  if (lane == 0) red[w] = v;
  __syncthreads();
  if (threadIdx.x == 0) bsum[blockIdx.x] = red[0] + red[1] + red[2] + red[3];
}
__global__ __launch_bounds__(256) void scan2_k(const int* __restrict__ bsum,
                                               int* __restrict__ boff,
                                               int* __restrict__ rowptrN, int nb) {
  __shared__ int ws[4];
  const int tid = threadIdx.x, lane = tid & 63, w = tid >> 6;
  int carry = 0;
  for (int base = 0; base < nb; base += 256) {
    int i = base + tid;
    int v = (i < nb) ? bsum[i] : 0;
    int inc = v;
    #pragma unroll
    for (int off = 1; off < 64; off <<= 1) {
      int n = __shfl_up(inc, off, 64);
      if (lane >= off) inc += n;
    }
    if (lane == 63) ws[w] = inc;
    __syncthreads();
    int woff = 0, tot = 0;
    #pragma unroll
    for (int k = 0; k < 4; ++k) { int s = ws[k]; if (k < w) woff += s; tot += s; }
    if (i < nb) boff[i] = carry + woff + inc - v;
    carry += tot;
    __syncthreads();
  }
  if (tid == 0) *rowptrN = carry;
}
__global__ __launch_bounds__(256) void scan3_k(const int* __restrict__ deg,
                                               const int* __restrict__ boff,
                                               int* __restrict__ rowptr,
                                               float* __restrict__ dinv, int N) {
  __shared__ int ws[4];
  int i = blockIdx.x * 256 + threadIdx.x;
  int lane = threadIdx.x & 63, w = threadIdx.x >> 6;
  int v = (i < N) ? deg[i] : 0;
  int inc = v;
  #pragma unroll
  for (int off = 1; off < 64; off <<= 1) {
    int n = __shfl_up(inc, off, 64);
    if (lane >= off) inc += n;
  }
  if (lane == 63) ws[w] = inc;
  __syncthreads();
  int woff = 0;
  #pragma unroll
  for (int k = 0; k < 4; ++k) if (k < w) woff += ws[k];
  if (i < N) {
    rowptr[i] = boff[blockIdx.x] + woff + inc - v;
    dinv[i] = rsqrtf((float)(v + 1));  // +1 self-loop
  }
}

// ---------- 3a. bucket cursor init ----------
__global__ void init_bcur_k(const int* __restrict__ rowptr, int* __restrict__ bcur,
                            int N, int NBKT) {
  int t = blockIdx.x * blockDim.x + threadIdx.x;
  if (t < NBKT) bcur[t] = rowptr[min(t << SPAN_SHIFT, N)];
}

// ---------- 3b. pass A: LDS radix-partition edges into dst-buckets ----------
__global__ __launch_bounds__(256) void scatterA_k(const int* __restrict__ ei,
    int* __restrict__ bcur, int2* __restrict__ tmp, int E,
    const int* __restrict__ flags, int NBKT) {
  __shared__ int2 stage[4096];                 // 32 KB
  __shared__ int hist[256], off[256], cnt2[256], gbase[256];
  __shared__ int wsum[4];
  const int tid = threadIdx.x;
  hist[tid] = 0; cnt2[tid] = 0;
  __syncthreads();
  const int base = blockIdx.x * 4096;
  const int i64 = flags[1];
  int rs[16], rd[16];
  #pragma unroll
  for (int j = 0; j < 16; ++j) {
    int e = base + j * 256 + tid;
    if (e < E) {
      int s, d;
      if (i64) { s = ei[2 * e]; d = ei[2 * (E + e)]; }
      else     { s = ei[e];     d = ei[E + e]; }
      rs[j] = s; rd[j] = d;
      atomicAdd(&hist[d >> SPAN_SHIFT], 1);
    } else rd[j] = -1;
  }
  __syncthreads();
  {
    int lane = tid & 63, w = tid >> 6;
    int v = hist[tid], inc = v;
    #pragma unroll
    for (int o = 1; o < 64; o <<= 1) { int n = __shfl_up(inc, o, 64); if (lane >= o) inc += n; }
    if (lane == 63) wsum[w] = inc;
    __syncthreads();
    int pre = 0;
    #pragma unroll
    for (int k = 0; k < 4; ++k) if (k < w) pre += wsum[k];
    off[tid] = pre + inc - v;
  }
  __syncthreads();
  #pragma unroll
  for (int j = 0; j < 16; ++j) {
    if (rd[j] >= 0) {
      int b = rd[j] >> SPAN_SHIFT;
      int r = atomicAdd(&cnt2[b], 1);
      int2 rec; rec.x = rs[j]; rec.y = rd[j];
      stage[off[b] + r] = rec;
    }
  }
  if (tid < NBKT && hist[tid] > 0) gbase[tid] = atomicAdd(&bcur[tid], hist[tid]);
  __syncthreads();
  const int total = off[255] + hist[255];
  for (int i = tid; i < total; i += 256) {
    int2 rec = stage[i];
    int b = rec.y >> SPAN_SHIFT;
    tmp[gbase[b] + (i - off[b])] = rec;
  }
}

// ---------- 3c. pass B: one block per bucket -> final CSR ----------
__global__ __launch_bounds__(256) void scatterB_k(const int2* __restrict__ tmp,
    const int* __restrict__ rowptr, const float* __restrict__ dinv,
    int2* __restrict__ spk, int N) {
  __shared__ int cur[256];
  const int tid = threadIdx.x;
  const int n0 = blockIdx.x << SPAN_SHIFT;
  const int n1 = min(n0 + 256, N);
  if (n0 + tid < n1) cur[tid] = rowptr[n0 + tid];
  __syncthreads();
  const int e0 = rowptr[n0], e1 = rowptr[n1];
  for (int i = e0 + tid; i < e1; i += 256) {
    int2 rec = tmp[i];
    int pos = atomicAdd(&cur[rec.y - n0], 1);
    int2 out; out.x = rec.x; out.y = __float_as_int(dinv[rec.x]);
    spk[pos] = out;
  }
}

// ---------- 4. MFMA GEMM: XWb[N,128](bf16) = X[N,128] @ W[128,128] ----------
// W staged directly from raw input (fp32 or bf16 per flags[wfi]).
__global__ __launch_bounds__(256) void gemm_k(const void* __restrict__ X,
                                              const void* __restrict__ Wraw,
                                              unsigned short* __restrict__ XWb, int N,
                                              const int* __restrict__ flags,
                                              int xmode, int wfi) {
  __shared__ unsigned short Wl[16384];     // swizzled frags, 32 KB
  __shared__ unsigned short Xl[64 * 136];  // row-major bf16, pad +8, 17.4 KB
  const int tid = threadIdx.x;
  const int xf32 = xmode ? 1 : flags[0];
  const int wf32 = flags[wfi];
  const int row0 = blockIdx.x * 64;
  // stage W: coalesced reads, swizzled bf16 LDS writes
  for (int v = tid; v < 4096; v += 256) {
    int k = v >> 5, n4 = (v & 31) * 4;
    unsigned short q0, q1, q2, q3;
    if (wf32) {
      float4 w4 = *(const float4*)&((const float*)Wraw)[k * 128 + n4];
      q0 = f2bf(w4.x); q1 = f2bf(w4.y); q2 = f2bf(w4.z); q3 = f2bf(w4.w);
    } else {
      ushort4 u = *(const ushort4*)&((const unsigned short*)Wraw)[k * 128 + n4];
      q0 = u.x; q1 = u.y; q2 = u.z; q3 = u.w;
    }
    int c = k >> 5, quad = (k >> 3) & 3, j = k & 7;
    int t = n4 >> 4;
    int colb = n4 & 15;
    int bb = ((c * 8 + t) * 64 + quad * 16 + colb) * 8 + j;
    Wl[bb]      = q0;
    Wl[bb + 8]  = q1;
    Wl[bb + 16] = q2;
    Wl[bb + 24] = q3;
  }
  // stage X rows (64 x 128) as bf16, row-major padded
  for (int v = tid; v < 2048; v += 256) {
    int r = v >> 5, k4 = (v & 31) * 4;
    int row = row0 + r;
    ushort4 u = make_ushort4(0, 0, 0, 0);
    if (row < N) {
      long long gi = (long long)row * 128 + k4;
      if (xf32) {
        float4 xv = *(const float4*)&((const float*)X)[gi];
        u.x = f2bf(xv.x); u.y = f2bf(xv.y); u.z = f2bf(xv.z); u.w = f2bf(xv.w);
      } else {
        u = *(const ushort4*)&((const unsigned short*)X)[gi];
      }
    }
    *(ushort4*)&Xl[r * 136 + k4] = u;
  }
  __syncthreads();
  const int w = tid >> 6, lane = tid & 63;
  const int quad = lane >> 4, col = lane & 15;
  float4v acc[8];
  #pragma unroll
  for (int t = 0; t < 8; ++t) acc[t] = (float4v){0.f, 0.f, 0.f, 0.f};
  #pragma unroll
  for (int c = 0; c < 4; ++c) {
    short8 a = *(const short8*)&Xl[(w * 16 + col) * 136 + c * 32 + quad * 8];
    #pragma unroll
    for (int t = 0; t < 8; ++t) {
      short8 b = *(const short8*)&Wl[((c * 8 + t) * 64 + lane) * 8];
      acc[t] = __builtin_amdgcn_mfma_f32_16x16x32_bf16(a, b, acc[t], 0, 0, 0);
    }
  }
  #pragma unroll
  for (int t = 0; t < 8; ++t) {
    #pragma unroll
    for (int r = 0; r < 4; ++r) {
      int row = row0 + w * 16 + quad * 4 + r;
      if (row < N) XWb[(long long)row * 128 + t * 16 + col] = f2bf(acc[t][r]);
    }
  }
}

// ---------- 5. aggregate (+ optional fused mean-pool accumulation) ----------
// One wave per node; 16-edge unroll = 8 gathers in flight.
// pool=1: instead of writing H, block-accumulate into LDS then one 128-atomic
// flush per (graph-uniform) block into accp.
__global__ __launch_bounds__(256) void aggregate_k(const unsigned short* __restrict__ XWb,
    const int* __restrict__ rowptr, const int2* __restrict__ spk,
    const float* __restrict__ dinv, const void* __restrict__ bias_raw, int bias_fi,
    float* __restrict__ H, int N, int relu,
    int pool, const int* __restrict__ batch, float* __restrict__ accp,
    const int* __restrict__ flags) {
  __shared__ float pacc[128];
  __shared__ int ginfo[4];
  const int tidb = threadIdx.x;
  const int wid = (blockIdx.x * 256 + tidb) >> 6;
  const bool valid = wid < N;
  const int lane = tidb & 63;
  const int half = lane >> 5;
  const int fl = (lane & 31) * 4;
  int beg = 0, end = 0;
  float di = 0.f;
  if (valid) { beg = rowptr[wid]; end = rowptr[wid + 1]; di = dinv[wid]; }
  float a0 = 0.f, a1 = 0.f, a2 = 0.f, a3 = 0.f;
  int idx = beg;
  for (; idx + 16 <= end; idx += 16) {
    int2 r0 = spk[idx + half];
    int2 r1 = spk[idx + 2 + half];
    int2 r2 = spk[idx + 4 + half];
    int2 r3 = spk[idx + 6 + half];
    int2 r4 = spk[idx + 8 + half];
    int2 r5 = spk[idx + 10 + half];
    int2 r6 = spk[idx + 12 + half];
    int2 r7 = spk[idx + 14 + half];
    ushort4 u0 = *(const ushort4*)&XWb[(long long)r0.x * 128 + fl];
    ushort4 u1 = *(const ushort4*)&XWb[(long long)r1.x * 128 + fl];
    ushort4 u2 = *(const ushort4*)&XWb[(long long)r2.x * 128 + fl];
    ushort4 u3 = *(const ushort4*)&XWb[(long long)r3.x * 128 + fl];
    ushort4 u4 = *(const ushort4*)&XWb[(long long)r4.x * 128 + fl];
    ushort4 u5 = *(const ushort4*)&XWb[(long long)r5.x * 128 + fl];
    ushort4 u6 = *(const ushort4*)&XWb[(long long)r6.x * 128 + fl];
    ushort4 u7 = *(const ushort4*)&XWb[(long long)r7.x * 128 + fl];
    float w0 = __int_as_float(r0.y), w1 = __int_as_float(r1.y);
    float w2 = __int_as_float(r2.y), w3 = __int_as_float(r3.y);
    float w4 = __int_as_float(r4.y), w5 = __int_as_float(r5.y);
    float w6 = __int_as_float(r6.y), w7 = __int_as_float(r7.y);
    a0 += w0 * bf2f(u0.x) + w1 * bf2f(u1.x) + w2 * bf2f(u2.x) + w3 * bf2f(u3.x)
        + w4 * bf2f(u4.x) + w5 * bf2f(u5.x) + w6 * bf2f(u6.x) + w7 * bf2f(u7.x);
    a1 += w0 * bf2f(u0.y) + w1 * bf2f(u1.y) + w2 * bf2f(u2.y) + w3 * bf2f(u3.y)
        + w4 * bf2f(u4.y) + w5 * bf2f(u5.y) + w6 * bf2f(u6.y) + w7 * bf2f(u7.y);
    a2 += w0 * bf2f(u0.z) + w1 * bf2f(u1.z) + w2 * bf2f(u2.z) + w3 * bf2f(u3.z)
        + w4 * bf2f(u4.z) + w5 * bf2f(u5.z) + w6 * bf2f(u6.z) + w7 * bf2f(u7.z);
    a3 += w0 * bf2f(u0.w) + w1 * bf2f(u1.w) + w2 * bf2f(u2.w) + w3 * bf2f(u3.w)
        + w4 * bf2f(u4.w) + w5 * bf2f(u5.w) + w6 * bf2f(u6.w) + w7 * bf2f(u7.w);
  }
  for (; idx + 8 <= end; idx += 8) {
    int2 rA = spk[idx + half];
    int2 rB = spk[idx + 2 + half];
    int2 rC = spk[idx + 4 + half];
    int2 rD = spk[idx + 6 + half];
    float wA = __int_as_float(rA.y), wB = __int_as_float(rB.y);
    float wC = __int_as_float(rC.y), wD = __int_as_float(rD.y);
    ushort4 uA = *(const ushort4*)&XWb[(long long)rA.x * 128 + fl];
    ushort4 uB = *(const ushort4*)&XWb[(long long)rB.x * 128 + fl];
    ushort4 uC = *(const ushort4*)&XWb[(long long)rC.x * 128 + fl];
    ushort4 uD = *(const ushort4*)&XWb[(long long)rD.x * 128 + fl];
    a0 += wA * bf2f(uA.x) + wB * bf2f(uB.x) + wC * bf2f(uC.x) + wD * bf2f(uD.x);
    a1 += wA * bf2f(uA.y) + wB * bf2f(uB.y) + wC * bf2f(uC.y) + wD * bf2f(uD.y);
    a2 += wA * bf2f(uA.z) + wB * bf2f(uB.z) + wC * bf2f(uC.z) + wD * bf2f(uD.z);
    a3 += wA * bf2f(uA.w) + wB * bf2f(uB.w) + wC * bf2f(uC.w) + wD * bf2f(uD.w);
  }
  if (idx + 4 <= end) {
    int2 rA = spk[idx + half];
    int2 rB = spk[idx + 2 + half];
    float wA = __int_as_float(rA.y), wB = __int_as_float(rB.y);
    ushort4 uA = *(const ushort4*)&XWb[(long long)rA.x * 128 + fl];
    ushort4 uB = *(const ushort4*)&XWb[(long long)rB.x * 128 + fl];
    a0 += wA * bf2f(uA.x) + wB * bf2f(uB.x);
    a1 += wA * bf2f(uA.y) + wB * bf2f(uB.y);
    a2 += wA * bf2f(uA.z) + wB * bf2f(uB.z);
    a3 += wA * bf2f(uA.w) + wB * bf2f(uB.w);
    idx += 4;
  }
  if (idx < end) {
    int iA = idx + half;
    int2 rA = spk[min(iA, end - 1)];
    float wA = (iA < end) ? __int_as_float(rA.y) : 0.f;
    ushort4 uA = *(const ushort4*)&XWb[(long long)rA.x * 128 + fl];
    a0 += wA * bf2f(uA.x); a1 += wA * bf2f(uA.y);
    a2 += wA * bf2f(uA.z); a3 += wA * bf2f(uA.w);
    if (idx + 2 < end) {
      int iB = idx + 2 + half;
      int2 rB = spk[min(iB, end - 1)];
      float wB = (iB < end) ? __int_as_float(rB.y) : 0.f;
      ushort4 uB = *(const ushort4*)&XWb[(long long)rB.x * 128 + fl];
      a0 += wB * bf2f(uB.x); a1 += wB * bf2f(uB.y);
      a2 += wB * bf2f(uB.z); a3 += wB * bf2f(uB.w);
    }
  }
  a0 += __shfl_xor(a0, 32, 64);
  a1 += __shfl_xor(a1, 32, 64);
  a2 += __shfl_xor(a2, 32, 64);
  a3 += __shfl_xor(a3, 32, 64);
  // epilogue values (half 0 lanes)
  float o0 = 0.f, o1 = 0.f, o2 = 0.f, o3 = 0.f;
  if (valid && half == 0) {
    ushort4 su = *(const ushort4*)&XWb[(long long)wid * 128 + fl];
    float d2 = di * di;
    o0 = di * a0 + d2 * bf2f(su.x);
    o1 = di * a1 + d2 * bf2f(su.y);
    o2 = di * a2 + d2 * bf2f(su.z);
    o3 = di * a3 + d2 * bf2f(su.w);
    if (bias_fi >= 0) {
      if (flags[bias_fi]) {
        float4 bv = *(const float4*)&((const float*)bias_raw)[fl];
        o0 += bv.x; o1 += bv.y; o2 += bv.z; o3 += bv.w;
      } else {
        const unsigned short* bu = (const unsigned short*)bias_raw;
        o0 += bf2f(bu[fl]); o1 += bf2f(bu[fl + 1]);
        o2 += bf2f(bu[fl + 2]); o3 += bf2f(bu[fl + 3]);
      }
    }
    if (relu) {
      o0 = fmaxf(o0, 0.f); o1 = fmaxf(o1, 0.f);
      o2 = fmaxf(o2, 0.f); o3 = fmaxf(o3, 0.f);
    }
  }
  if (!pool) {
    if (valid && half == 0)
      *(float4*)&H[(long long)wid * 128 + fl] = make_float4(o0, o1, o2, o3);
    return;
  }
  // fused pool: block-accumulate then flush
  const int w = tidb >> 6;
  if (lane == 0)
    ginfo[w] = valid ? (flags[1] ? batch[2 * wid] : batch[wid]) : -1;
  if (tidb < 128) pacc[tidb] = 0.f;
  __syncthreads();
  int gmax = -1; bool uni = true;
  #pragma unroll
  for (int k = 0; k < 4; ++k) {
    int g = ginfo[k];
    if (g >= 0) { if (gmax < 0) gmax = g; else if (g != gmax) uni = false; }
  }
  if (uni) {                       // block-uniform decision -> barrier-safe
    if (gmax < 0) return;
    if (valid && half == 0) {
      atomicAdd(&pacc[fl],     o0);
      atomicAdd(&pacc[fl + 1], o1);
      atomicAdd(&pacc[fl + 2], o2);
      atomicAdd(&pacc[fl + 3], o3);
    }
    __syncthreads();
    if (tidb < 128) atomicAdd(&accp[gmax * 128 + tidb], pacc[tidb]);
  } else {
    if (valid && half == 0) {
      int g = ginfo[w];
      atomicAdd(&accp[g * 128 + fl],     o0);
      atomicAdd(&accp[g * 128 + fl + 1], o1);
      atomicAdd(&accp[g * 128 + fl + 2], o2);
      atomicAdd(&accp[g * 128 + fl + 3], o3);
    }
  }
}

// ---------- 6. pool finalize: mean + b2 ----------
__global__ __launch_bounds__(128) void pool_final_k(const float* __restrict__ acc,
    const int* __restrict__ batch, const void* __restrict__ B2raw,
    float* __restrict__ out, int N, const int* __restrict__ flags) {
  __shared__ int sb[2];
  int g = blockIdx.x;
  int i64 = flags[1];
  if (threadIdx.x < 2) {
    int target = g + threadIdx.x;
    int lo = 0, hi = N;
    while (lo < hi) {
      int mid = (lo + hi) >> 1;
      int bv = i64 ? batch[2 * mid] : batch[mid];
      if (bv < target) lo = mid + 1; else hi = mid;
    }
    sb[threadIdx.x] = lo;
  }
  __syncthreads();
  int cnt = sb[1] - sb[0];
  int f = threadIdx.x;
  float b2 = flags[5] ? ((const float*)B2raw)[f]
                      : bf2f(((const unsigned short*)B2raw)[f]);
  float res = 0.f;
  if (cnt > 0) res = acc[g * 128 + f] / (float)cnt + b2;
  out[g * 128 + f] = res;
}

extern "C" void kernel_launch(void* const* d_in, const int* in_sizes, int n_in,
                              void* d_out, int out_size, void* d_ws, size_t ws_size,
                              hipStream_t stream) {
  const int N = in_sizes[0] / 128;   // 50000
  const int E = in_sizes[1] / 2;     // 800000
  const int G = out_size / 128;      // 64
  const int NB = (N + 255) / 256;
  const int NBKT = (N + 255) >> SPAN_SHIFT;

  const void* X  = d_in[0];
  const int*  EI = (const int*)d_in[1];
  const int*  BA = (const int*)d_in[2];
  const void* W1 = d_in[3];
  const void* B1 = d_in[4];
  const void* W2 = d_in[5];
  const void* B2 = d_in[6];
  float* OUT = (float*)d_out;

  char* ws = (char*)d_ws;
  size_t o = 0;
  auto alloc = [&](size_t b) { size_t r = o; o += (b + 255) & ~(size_t)255; return r; };
  int*   flags  = (int*)(ws + alloc(256));
  float* acc    = (float*)(ws + alloc((size_t)G * 128 * 4));
  int*   deg    = (int*)(ws + alloc((size_t)N * 4));
  int*   bsum   = (int*)(ws + alloc((size_t)NB * 4));
  int*   boff   = (int*)(ws + alloc((size_t)NB * 4));
  int*   bcur   = (int*)(ws + alloc(256 * 4));
  int*   rowptr = (int*)(ws + alloc((size_t)(N + 1) * 4));
  int2*  spk    = (int2*)(ws + alloc((size_t)E * 8));
  float* dinv   = (float*)(ws + alloc((size_t)N * 4));
  unsigned short* xwb = (unsigned short*)(ws + alloc((size_t)N * 128 * 2));
  float* h1     = (float*)(ws + alloc((size_t)N * 128 * 4));
  int2*  tmp    = (int2*)h1;   // bucket-partitioned edges; h1 dead until aggregate1

  const int TB = 256;
  detect_all_k<<<6, 256, 0, stream>>>((const unsigned short*)X, EI,
                                      (const unsigned short*)W1, (const unsigned short*)W2,
                                      (const unsigned short*)B1, (const unsigned short*)B2,
                                      flags);
  hipMemsetAsync(deg, 0, (size_t)N * 4, stream);
  hipMemsetAsync(acc, 0, (size_t)G * 128 * 4, stream);
  count_deg_k<<<(E + TB - 1) / TB, TB, 0, stream>>>(EI, deg, E, flags);
  scan1_k<<<NB, 256, 0, stream>>>(deg, bsum, N);
  scan2_k<<<1, 256, 0, stream>>>(bsum, boff, rowptr + N, NB);
  scan3_k<<<NB, 256, 0, stream>>>(deg, boff, rowptr, dinv, N);
  init_bcur_k<<<1, 256, 0, stream>>>(rowptr, bcur, N, NBKT);
  scatterA_k<<<(E + 4095) / 4096, 256, 0, stream>>>(EI, bcur, tmp, E, flags, NBKT);
  scatterB_k<<<NBKT, 256, 0, stream>>>(tmp, rowptr, dinv, spk, N);

  dim3 ggrid((N + 63) / 64);
  dim3 agrid((N * 64 + 255) / 256);

  // layer 1
  gemm_k<<<ggrid, 256, 0, stream>>>(X, W1, xwb, N, flags, 0, 2);
  aggregate_k<<<agrid, 256, 0, stream>>>(xwb, rowptr, spk, dinv, B1, 4, h1, N, 1,
                                         0, (const int*)nullptr, (float*)nullptr, flags);
  // layer 2 (pool fused into aggregate)
  gemm_k<<<ggrid, 256, 0, stream>>>(h1, W2, xwb, N, flags, 1, 3);
  aggregate_k<<<agrid, 256, 0, stream>>>(xwb, rowptr, spk, dinv, (const void*)nullptr, -1,
                                         (float*)nullptr, N, 0, 1, BA, acc, flags);
  // finalize
  pool_final_k<<<G, 128, 0, stream>>>(acc, BA, B2, OUT, N, flags);
}

// Round 10
// 292.011 us; speedup vs baseline: 1.1043x; 1.1043x over previous
//
#include <hip/hip_runtime.h>
#include <hip/hip_bf16.h>

#define SPAN_SHIFT 8   // dst-bucket span = 256 nodes

typedef __attribute__((ext_vector_type(8))) short short8;
typedef __attribute__((ext_vector_type(4))) float float4v;

// ---------- bf16 helpers (OCP bf16 = fp32 upper 16 bits) ----------
__device__ __forceinline__ float bf2f(unsigned short u) {
  union { unsigned int i; float f; } v; v.i = ((unsigned int)u) << 16; return v.f;
}
__device__ __forceinline__ unsigned short f2bf(float f) {
  union { float f; unsigned int i; } v; v.f = f;
  unsigned int x = v.i;
  return (unsigned short)((x + 0x7fffu + ((x >> 16) & 1u)) >> 16);  // RNE
}

// ---------- 0. dtype detection + workspace zeroing ----------
// flags[0]=x_fp32 flags[1]=int64 flags[2]=w1_fp32 flags[3]=w2_fp32 flags[4]=b1_fp32 flags[5]=b2_fp32
// blocks >=6 zero deg[0..N) and acc[0..G*128)
__global__ __launch_bounds__(256) void detect_zero_k(
    const unsigned short* __restrict__ xu,  const int* __restrict__ ei,
    const unsigned short* __restrict__ w1u, const unsigned short* __restrict__ w2u,
    const unsigned short* __restrict__ b1u, const unsigned short* __restrict__ b2u,
    int* __restrict__ flags, int* __restrict__ deg, float* __restrict__ acc,
    int N, int GP) {
  const int b = blockIdx.x;
  if (b >= 6) {                                   // zeroing blocks
    int base = (b - 6) * 4096 + threadIdx.x;
    #pragma unroll
    for (int j = 0; j < 16; ++j) {
      int i = base + j * 256;
      if (i < N) deg[i] = 0;
      else if (i < N + GP) acc[i - N] = 0.f;
    }
    return;
  }
  __shared__ int s_cnt;
  if (threadIdx.x == 0) s_cnt = 0;
  __syncthreads();
  int cnt = 0;
  if (b == 1) {  // int width: high words of int64 positives are all zero
    for (int i = threadIdx.x; i < 4096; i += 256)
      if (ei[2 * i + 1] == 0) cnt++;
    atomicAdd(&s_cnt, cnt);
    __syncthreads();
    if (threadIdx.x == 0) flags[1] = (s_cnt > 2048) ? 1 : 0;
    return;
  }
  const unsigned short* p; int n; int fi;
  if (b == 0)      { p = xu;  n = 16384; fi = 0; }
  else if (b == 2) { p = w1u; n = 16384; fi = 2; }
  else if (b == 3) { p = w2u; n = 16384; fi = 3; }
  else if (b == 4) { p = b1u; n = 128;   fi = 4; }
  else             { p = b2u; n = 128;   fi = 5; }
  for (int i = threadIdx.x; i < n; i += 256) {
    int e = (p[i] >> 7) & 0xFF;
    if (e < 96 || e > 159) cnt++;   // wild bf16 exponent => fp32 data
  }
  atomicAdd(&s_cnt, cnt);
  __syncthreads();
  if (threadIdx.x == 0) flags[fi] = (s_cnt * 8 > n) ? 1 : 0;
}

// ---------- shared GEMM body ----------
__device__ __forceinline__ void gemm_body(const void* __restrict__ X,
                                          const void* __restrict__ Wraw,
                                          unsigned short* __restrict__ XWb, int N,
                                          int xf32, int wf32, int row0,
                                          unsigned short* Wl, unsigned short* Xl) {
  const int tid = threadIdx.x;
  // stage W: coalesced reads, swizzled bf16 LDS writes
  for (int v = tid; v < 4096; v += 256) {
    int k = v >> 5, n4 = (v & 31) * 4;
    unsigned short q0, q1, q2, q3;
    if (wf32) {
      float4 w4 = *(const float4*)&((const float*)Wraw)[k * 128 + n4];
      q0 = f2bf(w4.x); q1 = f2bf(w4.y); q2 = f2bf(w4.z); q3 = f2bf(w4.w);
    } else {
      ushort4 u = *(const ushort4*)&((const unsigned short*)Wraw)[k * 128 + n4];
      q0 = u.x; q1 = u.y; q2 = u.z; q3 = u.w;
    }
    int c = k >> 5, quad = (k >> 3) & 3, j = k & 7;
    int t = n4 >> 4;
    int colb = n4 & 15;
    int bb = ((c * 8 + t) * 64 + quad * 16 + colb) * 8 + j;
    Wl[bb]      = q0;
    Wl[bb + 8]  = q1;
    Wl[bb + 16] = q2;
    Wl[bb + 24] = q3;
  }
  // stage X rows (64 x 128) as bf16, row-major padded (+8)
  for (int v = tid; v < 2048; v += 256) {
    int r = v >> 5, k4 = (v & 31) * 4;
    int row = row0 + r;
    ushort4 u = make_ushort4(0, 0, 0, 0);
    if (row < N) {
      long long gi = (long long)row * 128 + k4;
      if (xf32) {
        float4 xv = *(const float4*)&((const float*)X)[gi];
        u.x = f2bf(xv.x); u.y = f2bf(xv.y); u.z = f2bf(xv.z); u.w = f2bf(xv.w);
      } else {
        u = *(const ushort4*)&((const unsigned short*)X)[gi];
      }
    }
    *(ushort4*)&Xl[r * 136 + k4] = u;
  }
  __syncthreads();
  const int w = tid >> 6, lane = tid & 63;
  const int quad = lane >> 4, col = lane & 15;
  float4v acc[8];
  #pragma unroll
  for (int t = 0; t < 8; ++t) acc[t] = (float4v){0.f, 0.f, 0.f, 0.f};
  #pragma unroll
  for (int c = 0; c < 4; ++c) {
    short8 a = *(const short8*)&Xl[(w * 16 + col) * 136 + c * 32 + quad * 8];
    #pragma unroll
    for (int t = 0; t < 8; ++t) {
      short8 b = *(const short8*)&Wl[((c * 8 + t) * 64 + lane) * 8];
      acc[t] = __builtin_amdgcn_mfma_f32_16x16x32_bf16(a, b, acc[t], 0, 0, 0);
    }
  }
  #pragma unroll
  for (int t = 0; t < 8; ++t) {
    #pragma unroll
    for (int r = 0; r < 4; ++r) {
      int row = row0 + w * 16 + quad * 4 + r;
      if (row < N) XWb[(long long)row * 128 + t * 16 + col] = f2bf(acc[t][r]);
    }
  }
}

// ---------- 1. hybrid: gemm1 (blocks < GB) + degree count (blocks >= GB) ----------
__global__ __launch_bounds__(256) void gemm1_count_k(const void* __restrict__ X,
    const void* __restrict__ Wraw, unsigned short* __restrict__ XWb, int N,
    const int* __restrict__ flags, const int* __restrict__ ei,
    int* __restrict__ deg, int E, int GB) {
  __shared__ unsigned short Wl[16384];
  __shared__ unsigned short Xl[64 * 136];
  if ((int)blockIdx.x >= GB) {                    // degree-count blocks
    int e = ((int)blockIdx.x - GB) * 256 + threadIdx.x;
    if (e < E) {
      int d = flags[1] ? ei[2 * (E + e)] : ei[E + e];
      atomicAdd(&deg[d], 1);
    }
    return;
  }
  gemm_body(X, Wraw, XWb, N, flags[0], flags[2], blockIdx.x * 64, Wl, Xl);
}

// ---------- generic GEMM (layer 2: X fp32 for sure) ----------
__global__ __launch_bounds__(256) void gemm_k(const void* __restrict__ X,
                                              const void* __restrict__ Wraw,
                                              unsigned short* __restrict__ XWb, int N,
                                              const int* __restrict__ flags, int wfi) {
  __shared__ unsigned short Wl[16384];
  __shared__ unsigned short Xl[64 * 136];
  gemm_body(X, Wraw, XWb, N, 1, flags[wfi], blockIdx.x * 64, Wl, Xl);
}

// ---------- 2. hierarchical exclusive scan ----------
__global__ __launch_bounds__(256) void scan1_k(const int* __restrict__ deg,
                                               int* __restrict__ bsum, int N) {
  __shared__ int red[4];
  int i = blockIdx.x * 256 + threadIdx.x;
  int v = (i < N) ? deg[i] : 0;
  int lane = threadIdx.x & 63, w = threadIdx.x >> 6;
  #pragma unroll
  for (int off = 32; off > 0; off >>= 1) v += __shfl_down(v, off, 64);
  if (lane == 0) red[w] = v;
  __syncthreads();
  if (threadIdx.x == 0) bsum[blockIdx.x] = red[0] + red[1] + red[2] + red[3];
}
__global__ __launch_bounds__(256) void scan2_k(const int* __restrict__ bsum,
                                               int* __restrict__ boff,
                                               int* __restrict__ rowptrN, int nb) {
  __shared__ int ws[4];
  const int tid = threadIdx.x, lane = tid & 63, w = tid >> 6;
  int carry = 0;
  for (int base = 0; base < nb; base += 256) {
    int i = base + tid;
    int v = (i < nb) ? bsum[i] : 0;
    int inc = v;
    #pragma unroll
    for (int off = 1; off < 64; off <<= 1) {
      int n = __shfl_up(inc, off, 64);
      if (lane >= off) inc += n;
    }
    if (lane == 63) ws[w] = inc;
    __syncthreads();
    int woff = 0, tot = 0;
    #pragma unroll
    for (int k = 0; k < 4; ++k) { int s = ws[k]; if (k < w) woff += s; tot += s; }
    if (i < nb) boff[i] = carry + woff + inc - v;
    carry += tot;
    __syncthreads();
  }
  if (tid == 0) *rowptrN = carry;
}
// scan3 also seeds bcur: bucket b's start == boff[b] (256-aligned buckets)
__global__ __launch_bounds__(256) void scan3_k(const int* __restrict__ deg,
                                               const int* __restrict__ boff,
                                               int* __restrict__ rowptr,
                                               float* __restrict__ dinv,
                                               int* __restrict__ bcur, int N) {
  __shared__ int ws[4];
  int i = blockIdx.x * 256 + threadIdx.x;
  int lane = threadIdx.x & 63, w = threadIdx.x >> 6;
  int v = (i < N) ? deg[i] : 0;
  int inc = v;
  #pragma unroll
  for (int off = 1; off < 64; off <<= 1) {
    int n = __shfl_up(inc, off, 64);
    if (lane >= off) inc += n;
  }
  if (lane == 63) ws[w] = inc;
  __syncthreads();
  int woff = 0;
  #pragma unroll
  for (int k = 0; k < 4; ++k) if (k < w) woff += ws[k];
  if (i < N) {
    rowptr[i] = boff[blockIdx.x] + woff + inc - v;
    dinv[i] = rsqrtf((float)(v + 1));  // +1 self-loop
  }
  if (threadIdx.x == 0) bcur[blockIdx.x] = boff[blockIdx.x];
}

// ---------- 3a. pass A: LDS radix-partition edges into dst-buckets ----------
__global__ __launch_bounds__(256) void scatterA_k(const int* __restrict__ ei,
    int* __restrict__ bcur, int2* __restrict__ tmp, int E,
    const int* __restrict__ flags, int NBKT) {
  __shared__ int2 stage[4096];                 // 32 KB
  __shared__ int hist[256], off[256], cnt2[256], gbase[256];
  __shared__ int wsum[4];
  const int tid = threadIdx.x;
  hist[tid] = 0; cnt2[tid] = 0;
  __syncthreads();
  const int base = blockIdx.x * 4096;
  const int i64 = flags[1];
  int rs[16], rd[16];
  #pragma unroll
  for (int j = 0; j < 16; ++j) {
    int e = base + j * 256 + tid;
    if (e < E) {
      int s, d;
      if (i64) { s = ei[2 * e]; d = ei[2 * (E + e)]; }
      else     { s = ei[e];     d = ei[E + e]; }
      rs[j] = s; rd[j] = d;
      atomicAdd(&hist[d >> SPAN_SHIFT], 1);
    } else rd[j] = -1;
  }
  __syncthreads();
  {
    int lane = tid & 63, w = tid >> 6;
    int v = hist[tid], inc = v;
    #pragma unroll
    for (int o = 1; o < 64; o <<= 1) { int n = __shfl_up(inc, o, 64); if (lane >= o) inc += n; }
    if (lane == 63) wsum[w] = inc;
    __syncthreads();
    int pre = 0;
    #pragma unroll
    for (int k = 0; k < 4; ++k) if (k < w) pre += wsum[k];
    off[tid] = pre + inc - v;
  }
  __syncthreads();
  #pragma unroll
  for (int j = 0; j < 16; ++j) {
    if (rd[j] >= 0) {
      int b = rd[j] >> SPAN_SHIFT;
      int r = atomicAdd(&cnt2[b], 1);
      int2 rec; rec.x = rs[j]; rec.y = rd[j];
      stage[off[b] + r] = rec;
    }
  }
  if (tid < NBKT && hist[tid] > 0) gbase[tid] = atomicAdd(&bcur[tid], hist[tid]);
  __syncthreads();
  const int total = off[255] + hist[255];
  for (int i = tid; i < total; i += 256) {
    int2 rec = stage[i];
    int b = rec.y >> SPAN_SHIFT;
    tmp[gbase[b] + (i - off[b])] = rec;
  }
}

// ---------- 3b. pass B: one block per bucket -> final CSR ----------
__global__ __launch_bounds__(256) void scatterB_k(const int2* __restrict__ tmp,
    const int* __restrict__ rowptr, const float* __restrict__ dinv,
    int2* __restrict__ spk, int N) {
  __shared__ int cur[256];
  const int tid = threadIdx.x;
  const int n0 = blockIdx.x << SPAN_SHIFT;
  const int n1 = min(n0 + 256, N);
  if (n0 + tid < n1) cur[tid] = rowptr[n0 + tid];
  __syncthreads();
  const int e0 = rowptr[n0], e1 = rowptr[n1];
  for (int i = e0 + tid; i < e1; i += 256) {
    int2 rec = tmp[i];
    int pos = atomicAdd(&cur[rec.y - n0], 1);
    int2 out; out.x = rec.x; out.y = __float_as_int(dinv[rec.x]);
    spk[pos] = out;
  }
}

// ---------- 4. aggregate (round-8 proven structure: 8-edge unroll, early exit) ----------
__global__ __launch_bounds__(256) void aggregate_k(const unsigned short* __restrict__ XWb,
    const int* __restrict__ rowptr, const int2* __restrict__ spk,
    const float* __restrict__ dinv, const void* __restrict__ bias_raw, int bias_fi,
    float* __restrict__ H, int N, int relu, const int* __restrict__ flags) {
  int wid = (blockIdx.x * 256 + threadIdx.x) >> 6;  // one wave per node
  if (wid >= N) return;
  const int lane = threadIdx.x & 63;
  const int half = lane >> 5;
  const int fl = (lane & 31) * 4;
  const int beg = rowptr[wid], end = rowptr[wid + 1];
  const float di = dinv[wid];
  float a0 = 0.f, a1 = 0.f, a2 = 0.f, a3 = 0.f;
  int idx = beg;
  for (; idx + 8 <= end; idx += 8) {
    int2 rA = spk[idx + half];
    int2 rB = spk[idx + 2 + half];
    int2 rC = spk[idx + 4 + half];
    int2 rD = spk[idx + 6 + half];
    float wA = __int_as_float(rA.y), wB = __int_as_float(rB.y);
    float wC = __int_as_float(rC.y), wD = __int_as_float(rD.y);
    ushort4 uA = *(const ushort4*)&XWb[(long long)rA.x * 128 + fl];
    ushort4 uB = *(const ushort4*)&XWb[(long long)rB.x * 128 + fl];
    ushort4 uC = *(const ushort4*)&XWb[(long long)rC.x * 128 + fl];
    ushort4 uD = *(const ushort4*)&XWb[(long long)rD.x * 128 + fl];
    a0 += wA * bf2f(uA.x) + wB * bf2f(uB.x) + wC * bf2f(uC.x) + wD * bf2f(uD.x);
    a1 += wA * bf2f(uA.y) + wB * bf2f(uB.y) + wC * bf2f(uC.y) + wD * bf2f(uD.y);
    a2 += wA * bf2f(uA.z) + wB * bf2f(uB.z) + wC * bf2f(uC.z) + wD * bf2f(uD.z);
    a3 += wA * bf2f(uA.w) + wB * bf2f(uB.w) + wC * bf2f(uC.w) + wD * bf2f(uD.w);
  }
  if (idx + 4 <= end) {
    int2 rA = spk[idx + half];
    int2 rB = spk[idx + 2 + half];
    float wA = __int_as_float(rA.y), wB = __int_as_float(rB.y);
    ushort4 uA = *(const ushort4*)&XWb[(long long)rA.x * 128 + fl];
    ushort4 uB = *(const ushort4*)&XWb[(long long)rB.x * 128 + fl];
    a0 += wA * bf2f(uA.x) + wB * bf2f(uB.x);
    a1 += wA * bf2f(uA.y) + wB * bf2f(uB.y);
    a2 += wA * bf2f(uA.z) + wB * bf2f(uB.z);
    a3 += wA * bf2f(uA.w) + wB * bf2f(uB.w);
    idx += 4;
  }
  if (idx < end) {
    int iA = idx + half;
    int2 rA = spk[min(iA, end - 1)];
    float wA = (iA < end) ? __int_as_float(rA.y) : 0.f;
    ushort4 uA = *(const ushort4*)&XWb[(long long)rA.x * 128 + fl];
    a0 += wA * bf2f(uA.x); a1 += wA * bf2f(uA.y);
    a2 += wA * bf2f(uA.z); a3 += wA * bf2f(uA.w);
    if (idx + 2 < end) {
      int iB = idx + 2 + half;
      int2 rB = spk[min(iB, end - 1)];
      float wB = (iB < end) ? __int_as_float(rB.y) : 0.f;
      ushort4 uB = *(const ushort4*)&XWb[(long long)rB.x * 128 + fl];
      a0 += wB * bf2f(uB.x); a1 += wB * bf2f(uB.y);
      a2 += wB * bf2f(uB.z); a3 += wB * bf2f(uB.w);
    }
  }
  a0 += __shfl_xor(a0, 32, 64);
  a1 += __shfl_xor(a1, 32, 64);
  a2 += __shfl_xor(a2, 32, 64);
  a3 += __shfl_xor(a3, 32, 64);
  if (half == 0) {
    ushort4 su = *(const ushort4*)&XWb[(long long)wid * 128 + fl];
    float d2 = di * di;
    float o0 = di * a0 + d2 * bf2f(su.x);
    float o1 = di * a1 + d2 * bf2f(su.y);
    float o2 = di * a2 + d2 * bf2f(su.z);
    float o3 = di * a3 + d2 * bf2f(su.w);
    if (bias_fi >= 0) {
      if (flags[bias_fi]) {
        float4 bv = *(const float4*)&((const float*)bias_raw)[fl];
        o0 += bv.x; o1 += bv.y; o2 += bv.z; o3 += bv.w;
      } else {
        const unsigned short* bu = (const unsigned short*)bias_raw;
        o0 += bf2f(bu[fl]); o1 += bf2f(bu[fl + 1]);
        o2 += bf2f(bu[fl + 2]); o3 += bf2f(bu[fl + 3]);
      }
    }
    if (relu) {
      o0 = fmaxf(o0, 0.f); o1 = fmaxf(o1, 0.f);
      o2 = fmaxf(o2, 0.f); o3 = fmaxf(o3, 0.f);
    }
    *(float4*)&H[(long long)wid * 128 + fl] = make_float4(o0, o1, o2, o3);
  }
}

// ---------- 5a. pool phase A: per-wave run-length partial sums + atomic flush ----------
__global__ __launch_bounds__(256) void pool_partial_k(const float* __restrict__ H,
    const int* __restrict__ batch, float* __restrict__ acc, int N,
    const int* __restrict__ flags) {
  const int i64 = flags[1];
  const int lane = threadIdx.x & 63;
  const int w = threadIdx.x >> 6;
  const int chunk = (N + gridDim.x - 1) / gridDim.x;
  const int bstart = blockIdx.x * chunk;
  const int bend = min(bstart + chunk, N);
  const int sub = (chunk + 3) / 4;
  const int s = bstart + w * sub;
  const int e = min(s + sub, bend);
  if (s >= e) return;
  float ax = 0.f, ay = 0.f;
  int curg = i64 ? batch[2 * s] : batch[s];
  for (int n = s; n < e; ++n) {
    int g = i64 ? batch[2 * n] : batch[n];
    if (g != curg) {
      atomicAdd(&acc[curg * 128 + lane * 2], ax);
      atomicAdd(&acc[curg * 128 + lane * 2 + 1], ay);
      ax = ay = 0.f; curg = g;
    }
    float2 v = *(const float2*)&H[(long long)n * 128 + lane * 2];
    ax += v.x; ay += v.y;
  }
  atomicAdd(&acc[curg * 128 + lane * 2], ax);
  atomicAdd(&acc[curg * 128 + lane * 2 + 1], ay);
}

// ---------- 5b. pool finalize: mean + b2 ----------
__global__ __launch_bounds__(128) void pool_final_k(const float* __restrict__ acc,
    const int* __restrict__ batch, const void* __restrict__ B2raw,
    float* __restrict__ out, int N, const int* __restrict__ flags) {
  __shared__ int sb[2];
  int g = blockIdx.x;
  int i64 = flags[1];
  if (threadIdx.x < 2) {
    int target = g + threadIdx.x;
    int lo = 0, hi = N;
    while (lo < hi) {
      int mid = (lo + hi) >> 1;
      int bv = i64 ? batch[2 * mid] : batch[mid];
      if (bv < target) lo = mid + 1; else hi = mid;
    }
    sb[threadIdx.x] = lo;
  }
  __syncthreads();
  int cnt = sb[1] - sb[0];
  int f = threadIdx.x;
  float b2 = flags[5] ? ((const float*)B2raw)[f]
                      : bf2f(((const unsigned short*)B2raw)[f]);
  float res = 0.f;
  if (cnt > 0) res = acc[g * 128 + f] / (float)cnt + b2;
  out[g * 128 + f] = res;
}

extern "C" void kernel_launch(void* const* d_in, const int* in_sizes, int n_in,
                              void* d_out, int out_size, void* d_ws, size_t ws_size,
                              hipStream_t stream) {
  const int N = in_sizes[0] / 128;   // 50000
  const int E = in_sizes[1] / 2;     // 800000
  const int G = out_size / 128;      // 64
  const int NB = (N + 255) / 256;    // scan blocks == dst buckets
  const int GB = (N + 63) / 64;      // gemm blocks
  const int EB = (E + 255) / 256;    // count-deg blocks
  const int ZB = (N + G * 128 + 4095) / 4096;  // zeroing blocks

  const void* X  = d_in[0];
  const int*  EI = (const int*)d_in[1];
  const int*  BA = (const int*)d_in[2];
  const void* W1 = d_in[3];
  const void* B1 = d_in[4];
  const void* W2 = d_in[5];
  const void* B2 = d_in[6];
  float* OUT = (float*)d_out;

  char* ws = (char*)d_ws;
  size_t o = 0;
  auto alloc = [&](size_t b) { size_t r = o; o += (b + 255) & ~(size_t)255; return r; };
  int*   flags  = (int*)(ws + alloc(256));
  float* acc    = (float*)(ws + alloc((size_t)G * 128 * 4));
  int*   deg    = (int*)(ws + alloc((size_t)N * 4));
  int*   bsum   = (int*)(ws + alloc((size_t)NB * 4));
  int*   boff   = (int*)(ws + alloc((size_t)NB * 4));
  int*   bcur   = (int*)(ws + alloc((size_t)NB * 4));
  int*   rowptr = (int*)(ws + alloc((size_t)(N + 1) * 4));
  int2*  spk    = (int2*)(ws + alloc((size_t)E * 8));
  float* dinv   = (float*)(ws + alloc((size_t)N * 4));
  unsigned short* xwb = (unsigned short*)(ws + alloc((size_t)N * 128 * 2));
  float* h1     = (float*)(ws + alloc((size_t)N * 128 * 4));
  float* h2     = h1;          // h1 dead after gemm2 stages it
  int2*  tmp    = (int2*)h1;   // bucket-partitioned edges; h1 dead until aggregate1

  // 1. detect dtypes + zero deg/acc (one launch)
  detect_zero_k<<<6 + ZB, 256, 0, stream>>>((const unsigned short*)X, EI,
                                            (const unsigned short*)W1, (const unsigned short*)W2,
                                            (const unsigned short*)B1, (const unsigned short*)B2,
                                            flags, deg, acc, N, G * 128);
  // 2. hybrid: gemm1 + degree count (independent work, one launch)
  gemm1_count_k<<<GB + EB, 256, 0, stream>>>(X, W1, xwb, N, flags, EI, deg, E, GB);
  // 3. CSR build
  scan1_k<<<NB, 256, 0, stream>>>(deg, bsum, N);
  scan2_k<<<1, 256, 0, stream>>>(bsum, boff, rowptr + N, NB);
  scan3_k<<<NB, 256, 0, stream>>>(deg, boff, rowptr, dinv, bcur, N);
  scatterA_k<<<(E + 4095) / 4096, 256, 0, stream>>>(EI, bcur, tmp, E, flags, NB);
  scatterB_k<<<NB, 256, 0, stream>>>(tmp, rowptr, dinv, spk, N);

  dim3 agrid((N * 64 + 255) / 256);
  // layer 1 aggregate
  aggregate_k<<<agrid, 256, 0, stream>>>(xwb, rowptr, spk, dinv, B1, 4, h1, N, 1, flags);
  // layer 2
  gemm_k<<<GB, 256, 0, stream>>>(h1, W2, xwb, N, flags, 3);
  aggregate_k<<<agrid, 256, 0, stream>>>(xwb, rowptr, spk, dinv, (const void*)nullptr, -1,
                                         h2, N, 0, flags);
  // pool
  pool_partial_k<<<512, 256, 0, stream>>>(h2, BA, acc, N, flags);
  pool_final_k<<<G, 128, 0, stream>>>(acc, BA, B2, OUT, N, flags);
}

// Round 11
// 280.610 us; speedup vs baseline: 1.1492x; 1.0406x over previous
//
#include <hip/hip_runtime.h>
#include <hip/hip_bf16.h>

#define SPAN_SHIFT 8   // dst-bucket span = 256 nodes

typedef __attribute__((ext_vector_type(8))) short short8;
typedef __attribute__((ext_vector_type(4))) float float4v;

// ---------- bf16 helpers (OCP bf16 = fp32 upper 16 bits) ----------
__device__ __forceinline__ float bf2f(unsigned short u) {
  union { unsigned int i; float f; } v; v.i = ((unsigned int)u) << 16; return v.f;
}
__device__ __forceinline__ unsigned short f2bf(float f) {
  union { float f; unsigned int i; } v; v.f = f;
  unsigned int x = v.i;
  return (unsigned short)((x + 0x7fffu + ((x >> 16) & 1u)) >> 16);  // RNE
}

// ---------- 0. dtype detection + workspace zeroing ----------
// flags[0]=x_fp32 flags[1]=int64 flags[2]=w1_fp32 flags[3]=w2_fp32 flags[4]=b1_fp32 flags[5]=b2_fp32
__global__ __launch_bounds__(256) void detect_zero_k(
    const unsigned short* __restrict__ xu,  const int* __restrict__ ei,
    const unsigned short* __restrict__ w1u, const unsigned short* __restrict__ w2u,
    const unsigned short* __restrict__ b1u, const unsigned short* __restrict__ b2u,
    int* __restrict__ flags, int* __restrict__ deg, float* __restrict__ acc,
    int N, int GP) {
  const int b = blockIdx.x;
  if (b >= 6) {                                   // zeroing blocks
    int base = (b - 6) * 4096 + threadIdx.x;
    #pragma unroll
    for (int j = 0; j < 16; ++j) {
      int i = base + j * 256;
      if (i < N) deg[i] = 0;
      else if (i < N + GP) acc[i - N] = 0.f;
    }
    return;
  }
  __shared__ int s_cnt;
  if (threadIdx.x == 0) s_cnt = 0;
  __syncthreads();
  int cnt = 0;
  if (b == 1) {  // int width: high words of int64 positives are all zero
    for (int i = threadIdx.x; i < 4096; i += 256)
      if (ei[2 * i + 1] == 0) cnt++;
    atomicAdd(&s_cnt, cnt);
    __syncthreads();
    if (threadIdx.x == 0) flags[1] = (s_cnt > 2048) ? 1 : 0;
    return;
  }
  const unsigned short* p; int n; int fi;
  if (b == 0)      { p = xu;  n = 16384; fi = 0; }
  else if (b == 2) { p = w1u; n = 16384; fi = 2; }
  else if (b == 3) { p = w2u; n = 16384; fi = 3; }
  else if (b == 4) { p = b1u; n = 128;   fi = 4; }
  else             { p = b2u; n = 128;   fi = 5; }
  for (int i = threadIdx.x; i < n; i += 256) {
    int e = (p[i] >> 7) & 0xFF;
    if (e < 96 || e > 159) cnt++;   // wild bf16 exponent => fp32 data
  }
  atomicAdd(&s_cnt, cnt);
  __syncthreads();
  if (threadIdx.x == 0) flags[fi] = (s_cnt * 8 > n) ? 1 : 0;
}

// ---------- 0b. pre-swizzle W into MFMA B-fragment order (once, global) ----------
// out[((c*8+t)*64 + lane)*8 + j] = bf16(W[k=c*32+(lane>>4)*8+j][n=t*16+(lane&15)])
// GEMM staging then is a linear 16-B copy: conflict-free ds_write_b128.
__global__ __launch_bounds__(256) void swizzle_w_k(const void* __restrict__ W1,
    const void* __restrict__ W2, unsigned short* __restrict__ w1s,
    unsigned short* __restrict__ w2s, const int* __restrict__ flags) {
  const int b = blockIdx.x;
  const void* Wraw = (b < 64) ? W1 : W2;
  unsigned short* out = (b < 64) ? w1s : w2s;
  const int wf32 = (b < 64) ? flags[2] : flags[3];
  int u = (b & 63) * 256 + threadIdx.x;   // 0..16383
  int j = u & 7, lane = (u >> 3) & 63, blk = u >> 9;
  int c = blk >> 3, t = blk & 7;
  int quad = lane >> 4, col = lane & 15;
  int k = c * 32 + quad * 8 + j;
  int n = t * 16 + col;
  out[u] = wf32 ? f2bf(((const float*)Wraw)[k * 128 + n])
                : ((const unsigned short*)Wraw)[k * 128 + n];
}

// ---------- shared GEMM body (W pre-swizzled) ----------
__device__ __forceinline__ void gemm_body(const void* __restrict__ X,
                                          const unsigned short* __restrict__ Wsw,
                                          unsigned short* __restrict__ XWb, int N,
                                          int xf32, int row0,
                                          unsigned short* Wl, unsigned short* Xl) {
  const int tid = threadIdx.x;
  // stage W: linear 16-B copy (coalesced global, conflict-free LDS b128)
  for (int v = tid; v < 2048; v += 256)
    ((short8*)Wl)[v] = ((const short8*)Wsw)[v];
  // stage X rows (64 x 128) as bf16, row-major padded (+8)
  for (int v = tid; v < 2048; v += 256) {
    int r = v >> 5, k4 = (v & 31) * 4;
    int row = row0 + r;
    ushort4 u = make_ushort4(0, 0, 0, 0);
    if (row < N) {
      long long gi = (long long)row * 128 + k4;
      if (xf32) {
        float4 xv = *(const float4*)&((const float*)X)[gi];
        u.x = f2bf(xv.x); u.y = f2bf(xv.y); u.z = f2bf(xv.z); u.w = f2bf(xv.w);
      } else {
        u = *(const ushort4*)&((const unsigned short*)X)[gi];
      }
    }
    *(ushort4*)&Xl[r * 136 + k4] = u;
  }
  __syncthreads();
  const int w = tid >> 6, lane = tid & 63;
  const int quad = lane >> 4, col = lane & 15;
  float4v acc[8];
  #pragma unroll
  for (int t = 0; t < 8; ++t) acc[t] = (float4v){0.f, 0.f, 0.f, 0.f};
  #pragma unroll
  for (int c = 0; c < 4; ++c) {
    short8 a = *(const short8*)&Xl[(w * 16 + col) * 136 + c * 32 + quad * 8];
    #pragma unroll
    for (int t = 0; t < 8; ++t) {
      short8 b = *(const short8*)&Wl[((c * 8 + t) * 64 + lane) * 8];
      acc[t] = __builtin_amdgcn_mfma_f32_16x16x32_bf16(a, b, acc[t], 0, 0, 0);
    }
  }
  #pragma unroll
  for (int t = 0; t < 8; ++t) {
    #pragma unroll
    for (int r = 0; r < 4; ++r) {
      int row = row0 + w * 16 + quad * 4 + r;
      if (row < N) XWb[(long long)row * 128 + t * 16 + col] = f2bf(acc[t][r]);
    }
  }
}

// ---------- 1. hybrid: gemm1 (blocks < GB) + degree count (blocks >= GB) ----------
__global__ __launch_bounds__(256) void gemm1_count_k(const void* __restrict__ X,
    const unsigned short* __restrict__ Wsw, unsigned short* __restrict__ XWb, int N,
    const int* __restrict__ flags, const int* __restrict__ ei,
    int* __restrict__ deg, int E, int GB) {
  __shared__ __align__(16) unsigned short Wl[16384];
  __shared__ __align__(16) unsigned short Xl[64 * 136];
  if ((int)blockIdx.x >= GB) {                    // degree-count blocks
    int e = ((int)blockIdx.x - GB) * 256 + threadIdx.x;
    if (e < E) {
      int d = flags[1] ? ei[2 * (E + e)] : ei[E + e];
      atomicAdd(&deg[d], 1);
    }
    return;
  }
  gemm_body(X, Wsw, XWb, N, flags[0], blockIdx.x * 64, Wl, Xl);
}

// ---------- generic GEMM (layer 2: X fp32 for sure) ----------
__global__ __launch_bounds__(256) void gemm_k(const void* __restrict__ X,
                                              const unsigned short* __restrict__ Wsw,
                                              unsigned short* __restrict__ XWb, int N) {
  __shared__ __align__(16) unsigned short Wl[16384];
  __shared__ __align__(16) unsigned short Xl[64 * 136];
  gemm_body(X, Wsw, XWb, N, 1, blockIdx.x * 64, Wl, Xl);
}

// ---------- 2. hierarchical exclusive scan ----------
__global__ __launch_bounds__(256) void scan1_k(const int* __restrict__ deg,
                                               int* __restrict__ bsum, int N) {
  __shared__ int red[4];
  int i = blockIdx.x * 256 + threadIdx.x;
  int v = (i < N) ? deg[i] : 0;
  int lane = threadIdx.x & 63, w = threadIdx.x >> 6;
  #pragma unroll
  for (int off = 32; off > 0; off >>= 1) v += __shfl_down(v, off, 64);
  if (lane == 0) red[w] = v;
  __syncthreads();
  if (threadIdx.x == 0) bsum[blockIdx.x] = red[0] + red[1] + red[2] + red[3];
}
__global__ __launch_bounds__(256) void scan2_k(const int* __restrict__ bsum,
                                               int* __restrict__ boff,
                                               int* __restrict__ rowptrN, int nb) {
  __shared__ int ws[4];
  const int tid = threadIdx.x, lane = tid & 63, w = tid >> 6;
  int carry = 0;
  for (int base = 0; base < nb; base += 256) {
    int i = base + tid;
    int v = (i < nb) ? bsum[i] : 0;
    int inc = v;
    #pragma unroll
    for (int off = 1; off < 64; off <<= 1) {
      int n = __shfl_up(inc, off, 64);
      if (lane >= off) inc += n;
    }
    if (lane == 63) ws[w] = inc;
    __syncthreads();
    int woff = 0, tot = 0;
    #pragma unroll
    for (int k = 0; k < 4; ++k) { int s = ws[k]; if (k < w) woff += s; tot += s; }
    if (i < nb) boff[i] = carry + woff + inc - v;
    carry += tot;
    __syncthreads();
  }
  if (tid == 0) *rowptrN = carry;
}
// scan3 also seeds bcur: bucket b's start == boff[b] (256-aligned buckets)
__global__ __launch_bounds__(256) void scan3_k(const int* __restrict__ deg,
                                               const int* __restrict__ boff,
                                               int* __restrict__ rowptr,
                                               float* __restrict__ dinv,
                                               int* __restrict__ bcur, int N) {
  __shared__ int ws[4];
  int i = blockIdx.x * 256 + threadIdx.x;
  int lane = threadIdx.x & 63, w = threadIdx.x >> 6;
  int v = (i < N) ? deg[i] : 0;
  int inc = v;
  #pragma unroll
  for (int off = 1; off < 64; off <<= 1) {
    int n = __shfl_up(inc, off, 64);
    if (lane >= off) inc += n;
  }
  if (lane == 63) ws[w] = inc;
  __syncthreads();
  int woff = 0;
  #pragma unroll
  for (int k = 0; k < 4; ++k) if (k < w) woff += ws[k];
  if (i < N) {
    rowptr[i] = boff[blockIdx.x] + woff + inc - v;
    dinv[i] = rsqrtf((float)(v + 1));  // +1 self-loop
  }
  if (threadIdx.x == 0) bcur[blockIdx.x] = boff[blockIdx.x];
}

// ---------- 3a. pass A: LDS radix-partition edges into dst-buckets ----------
__global__ __launch_bounds__(256) void scatterA_k(const int* __restrict__ ei,
    int* __restrict__ bcur, int2* __restrict__ tmp, int E,
    const int* __restrict__ flags, int NBKT) {
  __shared__ int2 stage[4096];                 // 32 KB
  __shared__ int hist[256], off[256], cnt2[256], gbase[256];
  __shared__ int wsum[4];
  const int tid = threadIdx.x;
  hist[tid] = 0; cnt2[tid] = 0;
  __syncthreads();
  const int base = blockIdx.x * 4096;
  const int i64 = flags[1];
  int rs[16], rd[16];
  #pragma unroll
  for (int j = 0; j < 16; ++j) {
    int e = base + j * 256 + tid;
    if (e < E) {
      int s, d;
      if (i64) { s = ei[2 * e]; d = ei[2 * (E + e)]; }
      else     { s = ei[e];     d = ei[E + e]; }
      rs[j] = s; rd[j] = d;
      atomicAdd(&hist[d >> SPAN_SHIFT], 1);
    } else rd[j] = -1;
  }
  __syncthreads();
  {
    int lane = tid & 63, w = tid >> 6;
    int v = hist[tid], inc = v;
    #pragma unroll
    for (int o = 1; o < 64; o <<= 1) { int n = __shfl_up(inc, o, 64); if (lane >= o) inc += n; }
    if (lane == 63) wsum[w] = inc;
    __syncthreads();
    int pre = 0;
    #pragma unroll
    for (int k = 0; k < 4; ++k) if (k < w) pre += wsum[k];
    off[tid] = pre + inc - v;
  }
  __syncthreads();
  #pragma unroll
  for (int j = 0; j < 16; ++j) {
    if (rd[j] >= 0) {
      int b = rd[j] >> SPAN_SHIFT;
      int r = atomicAdd(&cnt2[b], 1);
      int2 rec; rec.x = rs[j]; rec.y = rd[j];
      stage[off[b] + r] = rec;
    }
  }
  if (tid < NBKT && hist[tid] > 0) gbase[tid] = atomicAdd(&bcur[tid], hist[tid]);
  __syncthreads();
  const int total = off[255] + hist[255];
  for (int i = tid; i < total; i += 256) {
    int2 rec = stage[i];
    int b = rec.y >> SPAN_SHIFT;
    tmp[gbase[b] + (i - off[b])] = rec;
  }
}

// ---------- 3b. pass B: one block per bucket -> final CSR ----------
__global__ __launch_bounds__(256) void scatterB_k(const int2* __restrict__ tmp,
    const int* __restrict__ rowptr, const float* __restrict__ dinv,
    int2* __restrict__ spk, int N) {
  __shared__ int cur[256];
  const int tid = threadIdx.x;
  const int n0 = blockIdx.x << SPAN_SHIFT;
  const int n1 = min(n0 + 256, N);
  if (n0 + tid < n1) cur[tid] = rowptr[n0 + tid];
  __syncthreads();
  const int e0 = rowptr[n0], e1 = rowptr[n1];
  for (int i = e0 + tid; i < e1; i += 256) {
    int2 rec = tmp[i];
    int pos = atomicAdd(&cur[rec.y - n0], 1);
    int2 out; out.x = rec.x; out.y = __float_as_int(dinv[rec.x]);
    spk[pos] = out;
  }
}

// ---------- 4. aggregate (8-edge unroll, early wave exit) ----------
__global__ __launch_bounds__(256) void aggregate_k(const unsigned short* __restrict__ XWb,
    const int* __restrict__ rowptr, const int2* __restrict__ spk,
    const float* __restrict__ dinv, const void* __restrict__ bias_raw, int bias_fi,
    float* __restrict__ H, int N, int relu, const int* __restrict__ flags) {
  int wid = (blockIdx.x * 256 + threadIdx.x) >> 6;  // one wave per node
  if (wid >= N) return;
  const int lane = threadIdx.x & 63;
  const int half = lane >> 5;
  const int fl = (lane & 31) * 4;
  const int beg = rowptr[wid], end = rowptr[wid + 1];
  const float di = dinv[wid];
  float a0 = 0.f, a1 = 0.f, a2 = 0.f, a3 = 0.f;
  int idx = beg;
  for (; idx + 8 <= end; idx += 8) {
    int2 rA = spk[idx + half];
    int2 rB = spk[idx + 2 + half];
    int2 rC = spk[idx + 4 + half];
    int2 rD = spk[idx + 6 + half];
    float wA = __int_as_float(rA.y), wB = __int_as_float(rB.y);
    float wC = __int_as_float(rC.y), wD = __int_as_float(rD.y);
    ushort4 uA = *(const ushort4*)&XWb[(long long)rA.x * 128 + fl];
    ushort4 uB = *(const ushort4*)&XWb[(long long)rB.x * 128 + fl];
    ushort4 uC = *(const ushort4*)&XWb[(long long)rC.x * 128 + fl];
    ushort4 uD = *(const ushort4*)&XWb[(long long)rD.x * 128 + fl];
    a0 += wA * bf2f(uA.x) + wB * bf2f(uB.x) + wC * bf2f(uC.x) + wD * bf2f(uD.x);
    a1 += wA * bf2f(uA.y) + wB * bf2f(uB.y) + wC * bf2f(uC.y) + wD * bf2f(uD.y);
    a2 += wA * bf2f(uA.z) + wB * bf2f(uB.z) + wC * bf2f(uC.z) + wD * bf2f(uD.z);
    a3 += wA * bf2f(uA.w) + wB * bf2f(uB.w) + wC * bf2f(uC.w) + wD * bf2f(uD.w);
  }
  if (idx + 4 <= end) {
    int2 rA = spk[idx + half];
    int2 rB = spk[idx + 2 + half];
    float wA = __int_as_float(rA.y), wB = __int_as_float(rB.y);
    ushort4 uA = *(const ushort4*)&XWb[(long long)rA.x * 128 + fl];
    ushort4 uB = *(const ushort4*)&XWb[(long long)rB.x * 128 + fl];
    a0 += wA * bf2f(uA.x) + wB * bf2f(uB.x);
    a1 += wA * bf2f(uA.y) + wB * bf2f(uB.y);
    a2 += wA * bf2f(uA.z) + wB * bf2f(uB.z);
    a3 += wA * bf2f(uA.w) + wB * bf2f(uB.w);
    idx += 4;
  }
  if (idx < end) {
    int iA = idx + half;
    int2 rA = spk[min(iA, end - 1)];
    float wA = (iA < end) ? __int_as_float(rA.y) : 0.f;
    ushort4 uA = *(const ushort4*)&XWb[(long long)rA.x * 128 + fl];
    a0 += wA * bf2f(uA.x); a1 += wA * bf2f(uA.y);
    a2 += wA * bf2f(uA.z); a3 += wA * bf2f(uA.w);
    if (idx + 2 < end) {
      int iB = idx + 2 + half;
      int2 rB = spk[min(iB, end - 1)];
      float wB = (iB < end) ? __int_as_float(rB.y) : 0.f;
      ushort4 uB = *(const ushort4*)&XWb[(long long)rB.x * 128 + fl];
      a0 += wB * bf2f(uB.x); a1 += wB * bf2f(uB.y);
      a2 += wB * bf2f(uB.z); a3 += wB * bf2f(uB.w);
    }
  }
  a0 += __shfl_xor(a0, 32, 64);
  a1 += __shfl_xor(a1, 32, 64);
  a2 += __shfl_xor(a2, 32, 64);
  a3 += __shfl_xor(a3, 32, 64);
  if (half == 0) {
    ushort4 su = *(const ushort4*)&XWb[(long long)wid * 128 + fl];
    float d2 = di * di;
    float o0 = di * a0 + d2 * bf2f(su.x);
    float o1 = di * a1 + d2 * bf2f(su.y);
    float o2 = di * a2 + d2 * bf2f(su.z);
    float o3 = di * a3 + d2 * bf2f(su.w);
    if (bias_fi >= 0) {
      if (flags[bias_fi]) {
        float4 bv = *(const float4*)&((const float*)bias_raw)[fl];
        o0 += bv.x; o1 += bv.y; o2 += bv.z; o3 += bv.w;
      } else {
        const unsigned short* bu = (const unsigned short*)bias_raw;
        o0 += bf2f(bu[fl]); o1 += bf2f(bu[fl + 1]);
        o2 += bf2f(bu[fl + 2]); o3 += bf2f(bu[fl + 3]);
      }
    }
    if (relu) {
      o0 = fmaxf(o0, 0.f); o1 = fmaxf(o1, 0.f);
      o2 = fmaxf(o2, 0.f); o3 = fmaxf(o3, 0.f);
    }
    *(float4*)&H[(long long)wid * 128 + fl] = make_float4(o0, o1, o2, o3);
  }
}

// ---------- 5a. pool phase A: per-wave run-length partial sums + atomic flush ----------
__global__ __launch_bounds__(256) void pool_partial_k(const float* __restrict__ H,
    const int* __restrict__ batch, float* __restrict__ acc, int N,
    const int* __restrict__ flags) {
  const int i64 = flags[1];
  const int lane = threadIdx.x & 63;
  const int w = threadIdx.x >> 6;
  const int chunk = (N + gridDim.x - 1) / gridDim.x;
  const int bstart = blockIdx.x * chunk;
  const int bend = min(bstart + chunk, N);
  const int sub = (chunk + 3) / 4;
  const int s = bstart + w * sub;
  const int e = min(s + sub, bend);
  if (s >= e) return;
  float ax = 0.f, ay = 0.f;
  int curg = i64 ? batch[2 * s] : batch[s];
  for (int n = s; n < e; ++n) {
    int g = i64 ? batch[2 * n] : batch[n];
    if (g != curg) {
      atomicAdd(&acc[curg * 128 + lane * 2], ax);
      atomicAdd(&acc[curg * 128 + lane * 2 + 1], ay);
      ax = ay = 0.f; curg = g;
    }
    float2 v = *(const float2*)&H[(long long)n * 128 + lane * 2];
    ax += v.x; ay += v.y;
  }
  atomicAdd(&acc[curg * 128 + lane * 2], ax);
  atomicAdd(&acc[curg * 128 + lane * 2 + 1], ay);
}

// ---------- 5b. pool finalize: mean + b2 ----------
__global__ __launch_bounds__(128) void pool_final_k(const float* __restrict__ acc,
    const int* __restrict__ batch, const void* __restrict__ B2raw,
    float* __restrict__ out, int N, const int* __restrict__ flags) {
  __shared__ int sb[2];
  int g = blockIdx.x;
  int i64 = flags[1];
  if (threadIdx.x < 2) {
    int target = g + threadIdx.x;
    int lo = 0, hi = N;
    while (lo < hi) {
      int mid = (lo + hi) >> 1;
      int bv = i64 ? batch[2 * mid] : batch[mid];
      if (bv < target) lo = mid + 1; else hi = mid;
    }
    sb[threadIdx.x] = lo;
  }
  __syncthreads();
  int cnt = sb[1] - sb[0];
  int f = threadIdx.x;
  float b2 = flags[5] ? ((const float*)B2raw)[f]
                      : bf2f(((const unsigned short*)B2raw)[f]);
  float res = 0.f;
  if (cnt > 0) res = acc[g * 128 + f] / (float)cnt + b2;
  out[g * 128 + f] = res;
}

extern "C" void kernel_launch(void* const* d_in, const int* in_sizes, int n_in,
                              void* d_out, int out_size, void* d_ws, size_t ws_size,
                              hipStream_t stream) {
  const int N = in_sizes[0] / 128;   // 50000
  const int E = in_sizes[1] / 2;     // 800000
  const int G = out_size / 128;      // 64
  const int NB = (N + 255) / 256;    // scan blocks == dst buckets
  const int GB = (N + 63) / 64;      // gemm blocks
  const int EB = (E + 255) / 256;    // count-deg blocks
  const int ZB = (N + G * 128 + 4095) / 4096;  // zeroing blocks

  const void* X  = d_in[0];
  const int*  EI = (const int*)d_in[1];
  const int*  BA = (const int*)d_in[2];
  const void* W1 = d_in[3];
  const void* B1 = d_in[4];
  const void* W2 = d_in[5];
  const void* B2 = d_in[6];
  float* OUT = (float*)d_out;

  char* ws = (char*)d_ws;
  size_t o = 0;
  auto alloc = [&](size_t b) { size_t r = o; o += (b + 255) & ~(size_t)255; return r; };
  int*   flags  = (int*)(ws + alloc(256));
  unsigned short* w1s = (unsigned short*)(ws + alloc(16384 * 2));  // pre-swizzled bf16
  unsigned short* w2s = (unsigned short*)(ws + alloc(16384 * 2));
  float* acc    = (float*)(ws + alloc((size_t)G * 128 * 4));
  int*   deg    = (int*)(ws + alloc((size_t)N * 4));
  int*   bsum   = (int*)(ws + alloc((size_t)NB * 4));
  int*   boff   = (int*)(ws + alloc((size_t)NB * 4));
  int*   bcur   = (int*)(ws + alloc((size_t)NB * 4));
  int*   rowptr = (int*)(ws + alloc((size_t)(N + 1) * 4));
  int2*  spk    = (int2*)(ws + alloc((size_t)E * 8));
  float* dinv   = (float*)(ws + alloc((size_t)N * 4));
  unsigned short* xwb = (unsigned short*)(ws + alloc((size_t)N * 128 * 2));
  float* h1     = (float*)(ws + alloc((size_t)N * 128 * 4));
  float* h2     = h1;          // h1 dead after gemm2 stages it
  int2*  tmp    = (int2*)h1;   // bucket-partitioned edges; h1 dead until aggregate1

  // 1. detect dtypes + zero deg/acc (one launch)
  detect_zero_k<<<6 + ZB, 256, 0, stream>>>((const unsigned short*)X, EI,
                                            (const unsigned short*)W1, (const unsigned short*)W2,
                                            (const unsigned short*)B1, (const unsigned short*)B2,
                                            flags, deg, acc, N, G * 128);
  // 1b. pre-swizzle both weight matrices (once)
  swizzle_w_k<<<128, 256, 0, stream>>>(W1, W2, w1s, w2s, flags);
  // 2. hybrid: gemm1 + degree count (independent work, one launch)
  gemm1_count_k<<<GB + EB, 256, 0, stream>>>(X, w1s, xwb, N, flags, EI, deg, E, GB);
  // 3. CSR build
  scan1_k<<<NB, 256, 0, stream>>>(deg, bsum, N);
  scan2_k<<<1, 256, 0, stream>>>(bsum, boff, rowptr + N, NB);
  scan3_k<<<NB, 256, 0, stream>>>(deg, boff, rowptr, dinv, bcur, N);
  scatterA_k<<<(E + 4095) / 4096, 256, 0, stream>>>(EI, bcur, tmp, E, flags, NB);
  scatterB_k<<<NB, 256, 0, stream>>>(tmp, rowptr, dinv, spk, N);

  dim3 agrid((N * 64 + 255) / 256);
  // layer 1 aggregate
  aggregate_k<<<agrid, 256, 0, stream>>>(xwb, rowptr, spk, dinv, B1, 4, h1, N, 1, flags);
  // layer 2
  gemm_k<<<GB, 256, 0, stream>>>(h1, w2s, xwb, N);
  aggregate_k<<<agrid, 256, 0, stream>>>(xwb, rowptr, spk, dinv, (const void*)nullptr, -1,
                                         h2, N, 0, flags);
  // pool
  pool_partial_k<<<512, 256, 0, stream>>>(h2, BA, acc, N, flags);
  pool_final_k<<<G, 128, 0, stream>>>(acc, BA, B2, OUT, N, flags);
}

// Round 12
// 245.862 us; speedup vs baseline: 1.3116x; 1.1413x over previous
//
#include <hip/hip_runtime.h>
#include <hip/hip_bf16.h>

#define SPAN_SHIFT 8      // dst-bucket span = 256 nodes
#define BCAP 8192         // per-bucket tmp capacity (mean ~4080, >60 sigma safety)

typedef __attribute__((ext_vector_type(8))) short short8;
typedef __attribute__((ext_vector_type(4))) float float4v;

// ---------- bf16 helpers (OCP bf16 = fp32 upper 16 bits) ----------
__device__ __forceinline__ float bf2f(unsigned short u) {
  union { unsigned int i; float f; } v; v.i = ((unsigned int)u) << 16; return v.f;
}
__device__ __forceinline__ unsigned short f2bf(float f) {
  union { float f; unsigned int i; } v; v.f = f;
  unsigned int x = v.i;
  return (unsigned short)((x + 0x7fffu + ((x >> 16) & 1u)) >> 16);  // RNE
}

// ---------- 0. dtype detection + zero bcnt/acc ----------
// flags[0]=x_fp32 flags[1]=int64 flags[2]=w1_fp32 flags[3]=w2_fp32 flags[4]=b1_fp32 flags[5]=b2_fp32
__global__ __launch_bounds__(256) void detect_zero_k(
    const unsigned short* __restrict__ xu,  const int* __restrict__ ei,
    const unsigned short* __restrict__ w1u, const unsigned short* __restrict__ w2u,
    const unsigned short* __restrict__ b1u, const unsigned short* __restrict__ b2u,
    int* __restrict__ flags, int* __restrict__ bcnt, float* __restrict__ acc,
    int NB, int GP) {
  const int b = blockIdx.x;
  if (b >= 6) {                                   // zeroing blocks
    int base = (b - 6) * 4096 + threadIdx.x;
    #pragma unroll
    for (int j = 0; j < 16; ++j) {
      int i = base + j * 256;
      if (i < NB) bcnt[i] = 0;
      else if (i < NB + GP) acc[i - NB] = 0.f;
    }
    return;
  }
  __shared__ int s_cnt;
  if (threadIdx.x == 0) s_cnt = 0;
  __syncthreads();
  int cnt = 0;
  if (b == 1) {  // int width: high words of int64 positives are all zero
    for (int i = threadIdx.x; i < 4096; i += 256)
      if (ei[2 * i + 1] == 0) cnt++;
    atomicAdd(&s_cnt, cnt);
    __syncthreads();
    if (threadIdx.x == 0) flags[1] = (s_cnt > 2048) ? 1 : 0;
    return;
  }
  const unsigned short* p; int n; int fi;
  if (b == 0)      { p = xu;  n = 16384; fi = 0; }
  else if (b == 2) { p = w1u; n = 16384; fi = 2; }
  else if (b == 3) { p = w2u; n = 16384; fi = 3; }
  else if (b == 4) { p = b1u; n = 128;   fi = 4; }
  else             { p = b2u; n = 128;   fi = 5; }
  for (int i = threadIdx.x; i < n; i += 256) {
    int e = (p[i] >> 7) & 0xFF;
    if (e < 96 || e > 159) cnt++;   // wild bf16 exponent => fp32 data
  }
  atomicAdd(&s_cnt, cnt);
  __syncthreads();
  if (threadIdx.x == 0) flags[fi] = (s_cnt * 8 > n) ? 1 : 0;
}

// ---------- 0b. pre-swizzle W into MFMA B-fragment order (once, global) ----------
__global__ __launch_bounds__(256) void swizzle_w_k(const void* __restrict__ W1,
    const void* __restrict__ W2, unsigned short* __restrict__ w1s,
    unsigned short* __restrict__ w2s, const int* __restrict__ flags) {
  const int b = blockIdx.x;
  const void* Wraw = (b < 64) ? W1 : W2;
  unsigned short* out = (b < 64) ? w1s : w2s;
  const int wf32 = (b < 64) ? flags[2] : flags[3];
  int u = (b & 63) * 256 + threadIdx.x;   // 0..16383
  int j = u & 7, lane = (u >> 3) & 63, blk = u >> 9;
  int c = blk >> 3, t = blk & 7;
  int quad = lane >> 4, col = lane & 15;
  int k = c * 32 + quad * 8 + j;
  int n = t * 16 + col;
  out[u] = wf32 ? f2bf(((const float*)Wraw)[k * 128 + n])
                : ((const unsigned short*)Wraw)[k * 128 + n];
}

// ---------- GEMM (W pre-swizzled; LDS-staged coalesced C-store) ----------
__global__ __launch_bounds__(256) void gemm_k(const void* __restrict__ X,
                                              const unsigned short* __restrict__ Wsw,
                                              unsigned short* __restrict__ XWb, int N,
                                              const int* __restrict__ flags, int xmode) {
  __shared__ __align__(16) unsigned short Wl[16384];
  __shared__ __align__(16) unsigned short Xl[64 * 136];
  const int tid = threadIdx.x;
  const int xf32 = xmode ? 1 : flags[0];
  const int row0 = blockIdx.x * 64;
  // stage W: linear 16-B copy (coalesced global, conflict-free LDS b128)
  for (int v = tid; v < 2048; v += 256)
    ((short8*)Wl)[v] = ((const short8*)Wsw)[v];
  // stage X rows (64 x 128) as bf16, row-major padded (+8)
  for (int v = tid; v < 2048; v += 256) {
    int r = v >> 5, k4 = (v & 31) * 4;
    int row = row0 + r;
    ushort4 u = make_ushort4(0, 0, 0, 0);
    if (row < N) {
      long long gi = (long long)row * 128 + k4;
      if (xf32) {
        float4 xv = *(const float4*)&((const float*)X)[gi];
        u.x = f2bf(xv.x); u.y = f2bf(xv.y); u.z = f2bf(xv.z); u.w = f2bf(xv.w);
      } else {
        u = *(const ushort4*)&((const unsigned short*)X)[gi];
      }
    }
    *(ushort4*)&Xl[r * 136 + k4] = u;
  }
  __syncthreads();
  const int w = tid >> 6, lane = tid & 63;
  const int quad = lane >> 4, col = lane & 15;
  float4v acc[8];
  #pragma unroll
  for (int t = 0; t < 8; ++t) acc[t] = (float4v){0.f, 0.f, 0.f, 0.f};
  #pragma unroll
  for (int c = 0; c < 4; ++c) {
    short8 a = *(const short8*)&Xl[(w * 16 + col) * 136 + c * 32 + quad * 8];
    #pragma unroll
    for (int t = 0; t < 8; ++t) {
      short8 b = *(const short8*)&Wl[((c * 8 + t) * 64 + lane) * 8];
      acc[t] = __builtin_amdgcn_mfma_f32_16x16x32_bf16(a, b, acc[t], 0, 0, 0);
    }
  }
  // C-store: write into own 16-row region of Xl (per-wave DS ops are in-order,
  // own region only -> no barrier needed), then coalesced ushort8 copy-out.
  #pragma unroll
  for (int t = 0; t < 8; ++t) {
    #pragma unroll
    for (int r = 0; r < 4; ++r)
      Xl[(w * 16 + quad * 4 + r) * 136 + t * 16 + col] = f2bf(acc[t][r]);
  }
  __syncthreads();
  for (int v = tid; v < 1024; v += 256) {       // 64 rows x 128 shorts, 16B chunks
    int r = v >> 4, ck = (v & 15) * 8;
    int row = row0 + r;
    if (row < N)
      *(short8*)&XWb[(long long)row * 128 + ck] = *(const short8*)&Xl[r * 136 + ck];
  }
}

// ---------- 1. scatterA: partition edges into fixed-capacity dst-buckets ----------
__global__ __launch_bounds__(256) void scatterA_k(const int* __restrict__ ei,
    int* __restrict__ bcnt, int2* __restrict__ tmp, int E,
    const int* __restrict__ flags, int NBKT) {
  __shared__ int2 stage[4096];                 // 32 KB
  __shared__ int hist[256], off[256], cnt2[256], gbase[256];
  __shared__ int wsum[4];
  const int tid = threadIdx.x;
  hist[tid] = 0; cnt2[tid] = 0;
  __syncthreads();
  const int base = blockIdx.x * 4096;
  const int i64 = flags[1];
  int rs[16], rd[16];
  #pragma unroll
  for (int j = 0; j < 16; ++j) {
    int e = base + j * 256 + tid;
    if (e < E) {
      int s, d;
      if (i64) { s = ei[2 * e]; d = ei[2 * (E + e)]; }
      else     { s = ei[e];     d = ei[E + e]; }
      rs[j] = s; rd[j] = d;
      atomicAdd(&hist[d >> SPAN_SHIFT], 1);
    } else rd[j] = -1;
  }
  __syncthreads();
  {
    int lane = tid & 63, w = tid >> 6;
    int v = hist[tid], inc = v;
    #pragma unroll
    for (int o = 1; o < 64; o <<= 1) { int n = __shfl_up(inc, o, 64); if (lane >= o) inc += n; }
    if (lane == 63) wsum[w] = inc;
    __syncthreads();
    int pre = 0;
    #pragma unroll
    for (int k = 0; k < 4; ++k) if (k < w) pre += wsum[k];
    off[tid] = pre + inc - v;
  }
  __syncthreads();
  #pragma unroll
  for (int j = 0; j < 16; ++j) {
    if (rd[j] >= 0) {
      int b = rd[j] >> SPAN_SHIFT;
      int r = atomicAdd(&cnt2[b], 1);
      int2 rec; rec.x = rs[j]; rec.y = rd[j];
      stage[off[b] + r] = rec;
    }
  }
  if (tid < NBKT && hist[tid] > 0)
    gbase[tid] = tid * BCAP + atomicAdd(&bcnt[tid], hist[tid]);
  __syncthreads();
  const int total = off[255] + hist[255];
  for (int i = tid; i < total; i += 256) {
    int2 rec = stage[i];
    int b = rec.y >> SPAN_SHIFT;
    tmp[gbase[b] + (i - off[b])] = rec;
  }
}

// ---------- 2. bucket scan: exclusive prefix of bucket counts ----------
__global__ __launch_bounds__(256) void bucket_scan_k(const int* __restrict__ bcnt,
    int* __restrict__ bbase, int* __restrict__ rowptrN, int NBKT, int E) {
  __shared__ int ws[4];
  const int tid = threadIdx.x, lane = tid & 63, w = tid >> 6;
  int v = (tid < NBKT) ? bcnt[tid] : 0;
  int inc = v;
  #pragma unroll
  for (int off = 1; off < 64; off <<= 1) {
    int n = __shfl_up(inc, off, 64);
    if (lane >= off) inc += n;
  }
  if (lane == 63) ws[w] = inc;
  __syncthreads();
  int pre = 0;
  #pragma unroll
  for (int k = 0; k < 4; ++k) if (k < w) pre += ws[k];
  if (tid < NBKT) bbase[tid] = pre + inc - v;
  if (tid == 0) *rowptrN = E;
}

// ---------- 3. scatB1: per-bucket histogram -> rowptr + dinv ----------
__global__ __launch_bounds__(256) void scatB1_k(const int2* __restrict__ tmp,
    const int* __restrict__ bcnt, const int* __restrict__ bbase,
    int* __restrict__ rowptr, float* __restrict__ dinv, int N) {
  __shared__ int hist[256];
  __shared__ int ws[4];
  const int tid = threadIdx.x;
  const int b = blockIdx.x;
  hist[tid] = 0;
  __syncthreads();
  const int cnt = bcnt[b];
  const int2* src = tmp + (long long)b * BCAP;
  for (int i = tid; i < cnt; i += 256)
    atomicAdd(&hist[src[i].y & 255], 1);
  __syncthreads();
  int v = hist[tid], inc = v;
  int lane = tid & 63, w = tid >> 6;
  #pragma unroll
  for (int off = 1; off < 64; off <<= 1) {
    int n = __shfl_up(inc, off, 64);
    if (lane >= off) inc += n;
  }
  if (lane == 63) ws[w] = inc;
  __syncthreads();
  int pre = 0;
  #pragma unroll
  for (int k = 0; k < 4; ++k) if (k < w) pre += ws[k];
  int node = (b << SPAN_SHIFT) + tid;
  if (node < N) {
    rowptr[node] = bbase[b] + pre + inc - v;
    dinv[node] = rsqrtf((float)(v + 1));   // +1 self-loop
  }
}

// ---------- 4. scatB2: place edges -> final CSR with dinv payload ----------
__global__ __launch_bounds__(256) void scatB2_k(const int2* __restrict__ tmp,
    const int* __restrict__ bcnt, const int* __restrict__ rowptr,
    const float* __restrict__ dinv, int2* __restrict__ spk, int N) {
  __shared__ int cur[256];
  const int tid = threadIdx.x;
  const int b = blockIdx.x;
  const int n0 = b << SPAN_SHIFT;
  if (n0 + tid < N) cur[tid] = rowptr[n0 + tid];
  __syncthreads();
  const int cnt = bcnt[b];
  const int2* src = tmp + (long long)b * BCAP;
  for (int i = tid; i < cnt; i += 256) {
    int2 rec = src[i];
    int pos = atomicAdd(&cur[rec.y & 255], 1);
    int2 out; out.x = rec.x; out.y = __float_as_int(dinv[rec.x]);
    spk[pos] = out;
  }
}

// ---------- 5. aggregate (8-edge unroll, early wave exit) ----------
__global__ __launch_bounds__(256) void aggregate_k(const unsigned short* __restrict__ XWb,
    const int* __restrict__ rowptr, const int2* __restrict__ spk,
    const float* __restrict__ dinv, const void* __restrict__ bias_raw, int bias_fi,
    float* __restrict__ H, int N, int relu, const int* __restrict__ flags) {
  int wid = (blockIdx.x * 256 + threadIdx.x) >> 6;  // one wave per node
  if (wid >= N) return;
  const int lane = threadIdx.x & 63;
  const int half = lane >> 5;
  const int fl = (lane & 31) * 4;
  const int beg = rowptr[wid], end = rowptr[wid + 1];
  const float di = dinv[wid];
  float a0 = 0.f, a1 = 0.f, a2 = 0.f, a3 = 0.f;
  int idx = beg;
  for (; idx + 8 <= end; idx += 8) {
    int2 rA = spk[idx + half];
    int2 rB = spk[idx + 2 + half];
    int2 rC = spk[idx + 4 + half];
    int2 rD = spk[idx + 6 + half];
    float wA = __int_as_float(rA.y), wB = __int_as_float(rB.y);
    float wC = __int_as_float(rC.y), wD = __int_as_float(rD.y);
    ushort4 uA = *(const ushort4*)&XWb[(long long)rA.x * 128 + fl];
    ushort4 uB = *(const ushort4*)&XWb[(long long)rB.x * 128 + fl];
    ushort4 uC = *(const ushort4*)&XWb[(long long)rC.x * 128 + fl];
    ushort4 uD = *(const ushort4*)&XWb[(long long)rD.x * 128 + fl];
    a0 += wA * bf2f(uA.x) + wB * bf2f(uB.x) + wC * bf2f(uC.x) + wD * bf2f(uD.x);
    a1 += wA * bf2f(uA.y) + wB * bf2f(uB.y) + wC * bf2f(uC.y) + wD * bf2f(uD.y);
    a2 += wA * bf2f(uA.z) + wB * bf2f(uB.z) + wC * bf2f(uC.z) + wD * bf2f(uD.z);
    a3 += wA * bf2f(uA.w) + wB * bf2f(uB.w) + wC * bf2f(uC.w) + wD * bf2f(uD.w);
  }
  if (idx + 4 <= end) {
    int2 rA = spk[idx + half];
    int2 rB = spk[idx + 2 + half];
    float wA = __int_as_float(rA.y), wB = __int_as_float(rB.y);
    ushort4 uA = *(const ushort4*)&XWb[(long long)rA.x * 128 + fl];
    ushort4 uB = *(const ushort4*)&XWb[(long long)rB.x * 128 + fl];
    a0 += wA * bf2f(uA.x) + wB * bf2f(uB.x);
    a1 += wA * bf2f(uA.y) + wB * bf2f(uB.y);
    a2 += wA * bf2f(uA.z) + wB * bf2f(uB.z);
    a3 += wA * bf2f(uA.w) + wB * bf2f(uB.w);
    idx += 4;
  }
  if (idx < end) {
    int iA = idx + half;
    int2 rA = spk[min(iA, end - 1)];
    float wA = (iA < end) ? __int_as_float(rA.y) : 0.f;
    ushort4 uA = *(const ushort4*)&XWb[(long long)rA.x * 128 + fl];
    a0 += wA * bf2f(uA.x); a1 += wA * bf2f(uA.y);
    a2 += wA * bf2f(uA.z); a3 += wA * bf2f(uA.w);
    if (idx + 2 < end) {
      int iB = idx + 2 + half;
      int2 rB = spk[min(iB, end - 1)];
      float wB = (iB < end) ? __int_as_float(rB.y) : 0.f;
      ushort4 uB = *(const ushort4*)&XWb[(long long)rB.x * 128 + fl];
      a0 += wB * bf2f(uB.x); a1 += wB * bf2f(uB.y);
      a2 += wB * bf2f(uB.z); a3 += wB * bf2f(uB.w);
    }
  }
  a0 += __shfl_xor(a0, 32, 64);
  a1 += __shfl_xor(a1, 32, 64);
  a2 += __shfl_xor(a2, 32, 64);
  a3 += __shfl_xor(a3, 32, 64);
  if (half == 0) {
    ushort4 su = *(const ushort4*)&XWb[(long long)wid * 128 + fl];
    float d2 = di * di;
    float o0 = di * a0 + d2 * bf2f(su.x);
    float o1 = di * a1 + d2 * bf2f(su.y);
    float o2 = di * a2 + d2 * bf2f(su.z);
    float o3 = di * a3 + d2 * bf2f(su.w);
    if (bias_fi >= 0) {
      if (flags[bias_fi]) {
        float4 bv = *(const float4*)&((const float*)bias_raw)[fl];
        o0 += bv.x; o1 += bv.y; o2 += bv.z; o3 += bv.w;
      } else {
        const unsigned short* bu = (const unsigned short*)bias_raw;
        o0 += bf2f(bu[fl]); o1 += bf2f(bu[fl + 1]);
        o2 += bf2f(bu[fl + 2]); o3 += bf2f(bu[fl + 3]);
      }
    }
    if (relu) {
      o0 = fmaxf(o0, 0.f); o1 = fmaxf(o1, 0.f);
      o2 = fmaxf(o2, 0.f); o3 = fmaxf(o3, 0.f);
    }
    *(float4*)&H[(long long)wid * 128 + fl] = make_float4(o0, o1, o2, o3);
  }
}

// ---------- 6a. pool phase A ----------
__global__ __launch_bounds__(256) void pool_partial_k(const float* __restrict__ H,
    const int* __restrict__ batch, float* __restrict__ acc, int N,
    const int* __restrict__ flags) {
  const int i64 = flags[1];
  const int lane = threadIdx.x & 63;
  const int w = threadIdx.x >> 6;
  const int chunk = (N + gridDim.x - 1) / gridDim.x;
  const int bstart = blockIdx.x * chunk;
  const int bend = min(bstart + chunk, N);
  const int sub = (chunk + 3) / 4;
  const int s = bstart + w * sub;
  const int e = min(s + sub, bend);
  if (s >= e) return;
  float ax = 0.f, ay = 0.f;
  int curg = i64 ? batch[2 * s] : batch[s];
  for (int n = s; n < e; ++n) {
    int g = i64 ? batch[2 * n] : batch[n];
    if (g != curg) {
      atomicAdd(&acc[curg * 128 + lane * 2], ax);
      atomicAdd(&acc[curg * 128 + lane * 2 + 1], ay);
      ax = ay = 0.f; curg = g;
    }
    float2 v = *(const float2*)&H[(long long)n * 128 + lane * 2];
    ax += v.x; ay += v.y;
  }
  atomicAdd(&acc[curg * 128 + lane * 2], ax);
  atomicAdd(&acc[curg * 128 + lane * 2 + 1], ay);
}

// ---------- 6b. pool finalize ----------
__global__ __launch_bounds__(128) void pool_final_k(const float* __restrict__ acc,
    const int* __restrict__ batch, const void* __restrict__ B2raw,
    float* __restrict__ out, int N, const int* __restrict__ flags) {
  __shared__ int sb[2];
  int g = blockIdx.x;
  int i64 = flags[1];
  if (threadIdx.x < 2) {
    int target = g + threadIdx.x;
    int lo = 0, hi = N;
    while (lo < hi) {
      int mid = (lo + hi) >> 1;
      int bv = i64 ? batch[2 * mid] : batch[mid];
      if (bv < target) lo = mid + 1; else hi = mid;
    }
    sb[threadIdx.x] = lo;
  }
  __syncthreads();
  int cnt = sb[1] - sb[0];
  int f = threadIdx.x;
  float b2 = flags[5] ? ((const float*)B2raw)[f]
                      : bf2f(((const unsigned short*)B2raw)[f]);
  float res = 0.f;
  if (cnt > 0) res = acc[g * 128 + f] / (float)cnt + b2;
  out[g * 128 + f] = res;
}

extern "C" void kernel_launch(void* const* d_in, const int* in_sizes, int n_in,
                              void* d_out, int out_size, void* d_ws, size_t ws_size,
                              hipStream_t stream) {
  const int N = in_sizes[0] / 128;   // 50000
  const int E = in_sizes[1] / 2;     // 800000
  const int G = out_size / 128;      // 64
  const int NB = (N + 255) >> SPAN_SHIFT;  // dst buckets (196), <=256
  const int GB = (N + 63) / 64;            // gemm blocks
  const int ZB = (NB + G * 128 + 4095) / 4096;  // zeroing blocks

  const void* X  = d_in[0];
  const int*  EI = (const int*)d_in[1];
  const int*  BA = (const int*)d_in[2];
  const void* W1 = d_in[3];
  const void* B1 = d_in[4];
  const void* W2 = d_in[5];
  const void* B2 = d_in[6];
  float* OUT = (float*)d_out;

  char* ws = (char*)d_ws;
  size_t o = 0;
  auto alloc = [&](size_t b) { size_t r = o; o += (b + 255) & ~(size_t)255; return r; };
  int*   flags  = (int*)(ws + alloc(256));
  unsigned short* w1s = (unsigned short*)(ws + alloc(16384 * 2));  // pre-swizzled bf16
  unsigned short* w2s = (unsigned short*)(ws + alloc(16384 * 2));
  float* acc    = (float*)(ws + alloc((size_t)G * 128 * 4));
  int*   bcnt   = (int*)(ws + alloc(256 * 4));
  int*   bbase  = (int*)(ws + alloc(256 * 4));
  int*   rowptr = (int*)(ws + alloc((size_t)(N + 1) * 4));
  int2*  spk    = (int2*)(ws + alloc((size_t)E * 8));
  float* dinv   = (float*)(ws + alloc((size_t)N * 4));
  unsigned short* xwb = (unsigned short*)(ws + alloc((size_t)N * 128 * 2));
  float* h1     = (float*)(ws + alloc((size_t)N * 128 * 4));
  float* h2     = h1;          // h1 dead after gemm2 stages it
  int2*  tmp    = (int2*)h1;   // bucket regions NB*BCAP*8 = 12.85 MB <= 25.6 MB; dead before aggregate1

  // 1. detect dtypes + zero bcnt/acc
  detect_zero_k<<<6 + ZB, 256, 0, stream>>>((const unsigned short*)X, EI,
                                            (const unsigned short*)W1, (const unsigned short*)W2,
                                            (const unsigned short*)B1, (const unsigned short*)B2,
                                            flags, bcnt, acc, NB, G * 128);
  // 1b. pre-swizzle both weight matrices
  swizzle_w_k<<<128, 256, 0, stream>>>(W1, W2, w1s, w2s, flags);
  // 2. gemm1 (pure)
  gemm_k<<<GB, 256, 0, stream>>>(X, w1s, xwb, N, flags, 0);
  // 3. CSR build (no degree pass: fixed-capacity buckets + per-bucket histograms)
  scatterA_k<<<(E + 4095) / 4096, 256, 0, stream>>>(EI, bcnt, tmp, E, flags, NB);
  bucket_scan_k<<<1, 256, 0, stream>>>(bcnt, bbase, rowptr + N, NB, E);
  scatB1_k<<<NB, 256, 0, stream>>>(tmp, bcnt, bbase, rowptr, dinv, N);
  scatB2_k<<<NB, 256, 0, stream>>>(tmp, bcnt, rowptr, dinv, spk, N);

  dim3 agrid((N * 64 + 255) / 256);
  // layer 1 aggregate
  aggregate_k<<<agrid, 256, 0, stream>>>(xwb, rowptr, spk, dinv, B1, 4, h1, N, 1, flags);
  // layer 2
  gemm_k<<<GB, 256, 0, stream>>>(h1, w2s, xwb, N, flags, 1);
  aggregate_k<<<agrid, 256, 0, stream>>>(xwb, rowptr, spk, dinv, (const void*)nullptr, -1,
                                         h2, N, 0, flags);
  // pool
  pool_partial_k<<<512, 256, 0, stream>>>(h2, BA, acc, N, flags);
  pool_final_k<<<G, 128, 0, stream>>>(acc, BA, B2, OUT, N, flags);
}

// Round 13
// 229.854 us; speedup vs baseline: 1.4029x; 1.0696x over previous
//
#include <hip/hip_runtime.h>
#include <hip/hip_bf16.h>

#define SPAN_SHIFT 8      // dst-bucket span = 256 nodes
#define BCAP 8192         // per-bucket tmp capacity (mean ~4080, >60 sigma safety)

typedef __attribute__((ext_vector_type(8))) short short8;
typedef __attribute__((ext_vector_type(4))) float float4v;

// ---------- bf16 helpers (OCP bf16 = fp32 upper 16 bits) ----------
__device__ __forceinline__ float bf2f(unsigned short u) {
  union { unsigned int i; float f; } v; v.i = ((unsigned int)u) << 16; return v.f;
}
__device__ __forceinline__ unsigned short f2bf(float f) {
  union { float f; unsigned int i; } v; v.f = f;
  unsigned int x = v.i;
  return (unsigned short)((x + 0x7fffu + ((x >> 16) & 1u)) >> 16);  // RNE
}

// ---------- 0. dtype probes + W pre-swizzle (self-probed) + zero bcnt/acc ----------
// flags[0]=x_fp32 flags[1]=int64 flags[4]=b1_fp32 flags[5]=b2_fp32
// blocks: 0..3 probes, 4..131 swizzle (W1:4..67, W2:68..131), 132.. zeroing
__global__ __launch_bounds__(256) void detect_swz_zero_k(
    const unsigned short* __restrict__ xu,  const int* __restrict__ ei,
    const unsigned short* __restrict__ b1u, const unsigned short* __restrict__ b2u,
    const void* __restrict__ W1, const void* __restrict__ W2,
    unsigned short* __restrict__ w1s, unsigned short* __restrict__ w2s,
    int* __restrict__ flags, int* __restrict__ bcnt, float* __restrict__ acc,
    int NBKT, int GP) {
  const int b = blockIdx.x;
  const int tid = threadIdx.x;
  if (b >= 132) {                                 // zeroing blocks
    int base = (b - 132) * 4096 + tid;
    #pragma unroll
    for (int j = 0; j < 16; ++j) {
      int i = base + j * 256;
      if (i < NBKT) bcnt[i] = 0;
      else if (i < NBKT + GP) acc[i - NBKT] = 0.f;
    }
    return;
  }
  __shared__ int s_cnt;
  if (tid == 0) s_cnt = 0;
  __syncthreads();
  if (b >= 4) {                                   // swizzle blocks, self-probe W dtype
    const void* Wraw = (b < 68) ? W1 : W2;
    unsigned short* out = (b < 68) ? w1s : w2s;
    const unsigned short* Wu = (const unsigned short*)Wraw;
    int c = 0;
    for (int i = tid; i < 512; i += 256) {
      int e = (Wu[i] >> 7) & 0xFF;
      if (e < 96 || e > 159) c++;                 // fp32 halves look wild as bf16
    }
    atomicAdd(&s_cnt, c);
    __syncthreads();
    const int wf32 = s_cnt > 64;
    int u = ((b - 4) & 63) * 256 + tid;           // 0..16383
    int j = u & 7, lane = (u >> 3) & 63, blk = u >> 9;
    int cc = blk >> 3, t = blk & 7;
    int quad = lane >> 4, col = lane & 15;
    int k = cc * 32 + quad * 8 + j;
    int n = t * 16 + col;
    out[u] = wf32 ? f2bf(((const float*)Wraw)[k * 128 + n])
                  : ((const unsigned short*)Wraw)[k * 128 + n];
    return;
  }
  int cnt = 0;
  if (b == 1) {  // int width: high words of int64 positives are all zero
    for (int i = tid; i < 4096; i += 256)
      if (ei[2 * i + 1] == 0) cnt++;
    atomicAdd(&s_cnt, cnt);
    __syncthreads();
    if (tid == 0) flags[1] = (s_cnt > 2048) ? 1 : 0;
    return;
  }
  const unsigned short* p; int n; int fi;
  if (b == 0)      { p = xu;  n = 16384; fi = 0; }
  else if (b == 2) { p = b1u; n = 128;   fi = 4; }
  else             { p = b2u; n = 128;   fi = 5; }
  for (int i = tid; i < n; i += 256) {
    int e = (p[i] >> 7) & 0xFF;
    if (e < 96 || e > 159) cnt++;
  }
  atomicAdd(&s_cnt, cnt);
  __syncthreads();
  if (tid == 0) flags[fi] = (s_cnt * 8 > n) ? 1 : 0;
}

// ---------- shared GEMM body (W pre-swizzled; LDS-staged coalesced C-store) ----------
// xf32: 1 = X fp32, 0 = X bf16
__device__ __forceinline__ void gemm_body(const void* __restrict__ X,
                                          const unsigned short* __restrict__ Wsw,
                                          unsigned short* __restrict__ XWb, int N,
                                          int xf32, int row0,
                                          unsigned short* Wl, unsigned short* Xl) {
  const int tid = threadIdx.x;
  for (int v = tid; v < 2048; v += 256)           // W: linear conflict-free copy
    ((short8*)Wl)[v] = ((const short8*)Wsw)[v];
  for (int v = tid; v < 2048; v += 256) {         // X: 64 rows x 128, bf16, pad +8
    int r = v >> 5, k4 = (v & 31) * 4;
    int row = row0 + r;
    ushort4 u = make_ushort4(0, 0, 0, 0);
    if (row < N) {
      long long gi = (long long)row * 128 + k4;
      if (xf32) {
        float4 xv = *(const float4*)&((const float*)X)[gi];
        u.x = f2bf(xv.x); u.y = f2bf(xv.y); u.z = f2bf(xv.z); u.w = f2bf(xv.w);
      } else {
        u = *(const ushort4*)&((const unsigned short*)X)[gi];
      }
    }
    *(ushort4*)&Xl[r * 136 + k4] = u;
  }
  __syncthreads();
  const int w = tid >> 6, lane = tid & 63;
  const int quad = lane >> 4, col = lane & 15;
  float4v acc[8];
  #pragma unroll
  for (int t = 0; t < 8; ++t) acc[t] = (float4v){0.f, 0.f, 0.f, 0.f};
  #pragma unroll
  for (int c = 0; c < 4; ++c) {
    short8 a = *(const short8*)&Xl[(w * 16 + col) * 136 + c * 32 + quad * 8];
    #pragma unroll
    for (int t = 0; t < 8; ++t) {
      short8 b = *(const short8*)&Wl[((c * 8 + t) * 64 + lane) * 8];
      acc[t] = __builtin_amdgcn_mfma_f32_16x16x32_bf16(a, b, acc[t], 0, 0, 0);
    }
  }
  // C-store via own 16-row LDS region, then coalesced 16-B copy-out
  #pragma unroll
  for (int t = 0; t < 8; ++t) {
    #pragma unroll
    for (int r = 0; r < 4; ++r)
      Xl[(w * 16 + quad * 4 + r) * 136 + t * 16 + col] = f2bf(acc[t][r]);
  }
  __syncthreads();
  for (int v = tid; v < 1024; v += 256) {
    int r = v >> 4, ck = (v & 15) * 8;
    int row = row0 + r;
    if (row < N)
      *(short8*)&XWb[(long long)row * 128 + ck] = *(const short8*)&Xl[r * 136 + ck];
  }
}

// ---------- 1. fused: scatterA (blocks < SA) + gemm1 (blocks >= SA) ----------
// Both halves genuinely need big LDS (36KB / 49.4KB) -> no occupancy trap.
__global__ __launch_bounds__(256) void scatA_gemm1_k(const int* __restrict__ ei,
    int* __restrict__ bcnt, int2* __restrict__ tmp, int E, int SA,
    const void* __restrict__ X, const unsigned short* __restrict__ Wsw,
    unsigned short* __restrict__ XWb, int N,
    const int* __restrict__ flags, int NBKT) {
  __shared__ __align__(16) char smem[50688];
  const int tid = threadIdx.x;
  if ((int)blockIdx.x >= SA) {                    // gemm1 blocks
    unsigned short* Wl = (unsigned short*)smem;          // 32 KB
    unsigned short* Xl = (unsigned short*)(smem + 32768); // 17.4 KB
    gemm_body(X, Wsw, XWb, N, flags[0], ((int)blockIdx.x - SA) * 64, Wl, Xl);
    return;
  }
  // ---- scatterA body ----
  int2* stage = (int2*)smem;                      // 32 KB
  int* hist  = (int*)(smem + 32768);
  int* off   = hist + 256;
  int* cnt2  = off + 256;
  int* gbase = cnt2 + 256;
  int* wsum  = gbase + 256;
  hist[tid] = 0; cnt2[tid] = 0;
  __syncthreads();
  const int base = blockIdx.x * 4096;
  const int i64 = flags[1];
  int rs[16], rd[16];
  #pragma unroll
  for (int j = 0; j < 16; ++j) {
    int e = base + j * 256 + tid;
    if (e < E) {
      int s, d;
      if (i64) { s = ei[2 * e]; d = ei[2 * (E + e)]; }
      else     { s = ei[e];     d = ei[E + e]; }
      rs[j] = s; rd[j] = d;
      atomicAdd(&hist[d >> SPAN_SHIFT], 1);
    } else rd[j] = -1;
  }
  __syncthreads();
  {
    int lane = tid & 63, w = tid >> 6;
    int v = hist[tid], inc = v;
    #pragma unroll
    for (int o = 1; o < 64; o <<= 1) { int n = __shfl_up(inc, o, 64); if (lane >= o) inc += n; }
    if (lane == 63) wsum[w] = inc;
    __syncthreads();
    int pre = 0;
    #pragma unroll
    for (int k = 0; k < 4; ++k) if (k < w) pre += wsum[k];
    off[tid] = pre + inc - v;
  }
  __syncthreads();
  #pragma unroll
  for (int j = 0; j < 16; ++j) {
    if (rd[j] >= 0) {
      int b = rd[j] >> SPAN_SHIFT;
      int r = atomicAdd(&cnt2[b], 1);
      int2 rec; rec.x = rs[j]; rec.y = rd[j];
      stage[off[b] + r] = rec;
    }
  }
  if (tid < NBKT && hist[tid] > 0)
    gbase[tid] = tid * BCAP + atomicAdd(&bcnt[tid], hist[tid]);
  __syncthreads();
  const int total = off[255] + hist[255];
  for (int i = tid; i < total; i += 256) {
    int2 rec = stage[i];
    int b = rec.y >> SPAN_SHIFT;
    tmp[gbase[b] + (i - off[b])] = rec;
  }
}

// ---------- generic GEMM (xmode: 1 = fp32 input, 2 = bf16 input) ----------
__global__ __launch_bounds__(256) void gemm_k(const void* __restrict__ X,
                                              const unsigned short* __restrict__ Wsw,
                                              unsigned short* __restrict__ XWb, int N,
                                              int xmode) {
  __shared__ __align__(16) unsigned short Wl[16384];
  __shared__ __align__(16) unsigned short Xl[64 * 136];
  gemm_body(X, Wsw, XWb, N, (xmode == 1) ? 1 : 0, blockIdx.x * 64, Wl, Xl);
}

// ---------- 2. scatB1: self prefix + per-bucket histogram -> rowptr + dinv ----------
__global__ __launch_bounds__(256) void scatB1_k(const int2* __restrict__ tmp,
    const int* __restrict__ bcnt, int* __restrict__ rowptr,
    float* __restrict__ dinv, int N, int NBKT, int E) {
  __shared__ int hist[256];
  __shared__ int pfx[256];
  __shared__ int ws[4];
  const int tid = threadIdx.x;
  const int b = blockIdx.x;
  const int lane = tid & 63, w = tid >> 6;
  // global prefix over bucket counts (every block computes it; 196 ints, L2-hot)
  int c = (tid < NBKT) ? bcnt[tid] : 0;
  hist[tid] = 0;
  {
    int inc = c;
    #pragma unroll
    for (int o = 1; o < 64; o <<= 1) { int n = __shfl_up(inc, o, 64); if (lane >= o) inc += n; }
    if (lane == 63) ws[w] = inc;
    __syncthreads();
    int pre = 0;
    #pragma unroll
    for (int k = 0; k < 4; ++k) if (k < w) pre += ws[k];
    pfx[tid] = pre + inc - c;
  }
  __syncthreads();
  const int bbase = pfx[b];
  const int cnt = bcnt[b];
  const int2* src = tmp + (long long)b * BCAP;
  for (int i = tid; i < cnt; i += 256)
    atomicAdd(&hist[src[i].y & 255], 1);
  __syncthreads();
  int v = hist[tid], inc = v;
  #pragma unroll
  for (int o = 1; o < 64; o <<= 1) {
    int n = __shfl_up(inc, o, 64);
    if (lane >= o) inc += n;
  }
  if (lane == 63) ws[w] = inc;
  __syncthreads();
  int pre = 0;
  #pragma unroll
  for (int k = 0; k < 4; ++k) if (k < w) pre += ws[k];
  int node = (b << SPAN_SHIFT) + tid;
  if (node < N) {
    rowptr[node] = bbase + pre + inc - v;
    dinv[node] = rsqrtf((float)(v + 1));   // +1 self-loop
  }
  if (b == 0 && tid == 0) rowptr[N] = E;
}

// ---------- 3. scatB2: place edges -> final CSR with dinv payload ----------
__global__ __launch_bounds__(256) void scatB2_k(const int2* __restrict__ tmp,
    const int* __restrict__ bcnt, const int* __restrict__ rowptr,
    const float* __restrict__ dinv, int2* __restrict__ spk, int N) {
  __shared__ int cur[256];
  const int tid = threadIdx.x;
  const int b = blockIdx.x;
  const int n0 = b << SPAN_SHIFT;
  if (n0 + tid < N) cur[tid] = rowptr[n0 + tid];
  __syncthreads();
  const int cnt = bcnt[b];
  const int2* src = tmp + (long long)b * BCAP;
  for (int i = tid; i < cnt; i += 256) {
    int2 rec = src[i];
    int pos = atomicAdd(&cur[rec.y & 255], 1);
    int2 out; out.x = rec.x; out.y = __float_as_int(dinv[rec.x]);
    spk[pos] = out;
  }
}

// ---------- 4. aggregate (8-edge unroll, early wave exit; optional bf16 out) ----------
__global__ __launch_bounds__(256) void aggregate_k(const unsigned short* __restrict__ XWb,
    const int* __restrict__ rowptr, const int2* __restrict__ spk,
    const float* __restrict__ dinv, const void* __restrict__ bias_raw, int bias_fi,
    void* __restrict__ H, int N, int relu, int out_bf16,
    const int* __restrict__ flags) {
  int wid = (blockIdx.x * 256 + threadIdx.x) >> 6;  // one wave per node
  if (wid >= N) return;
  const int lane = threadIdx.x & 63;
  const int half = lane >> 5;
  const int fl = (lane & 31) * 4;
  const int beg = rowptr[wid], end = rowptr[wid + 1];
  const float di = dinv[wid];
  float a0 = 0.f, a1 = 0.f, a2 = 0.f, a3 = 0.f;
  int idx = beg;
  for (; idx + 8 <= end; idx += 8) {
    int2 rA = spk[idx + half];
    int2 rB = spk[idx + 2 + half];
    int2 rC = spk[idx + 4 + half];
    int2 rD = spk[idx + 6 + half];
    float wA = __int_as_float(rA.y), wB = __int_as_float(rB.y);
    float wC = __int_as_float(rC.y), wD = __int_as_float(rD.y);
    ushort4 uA = *(const ushort4*)&XWb[(long long)rA.x * 128 + fl];
    ushort4 uB = *(const ushort4*)&XWb[(long long)rB.x * 128 + fl];
    ushort4 uC = *(const ushort4*)&XWb[(long long)rC.x * 128 + fl];
    ushort4 uD = *(const ushort4*)&XWb[(long long)rD.x * 128 + fl];
    a0 += wA * bf2f(uA.x) + wB * bf2f(uB.x) + wC * bf2f(uC.x) + wD * bf2f(uD.x);
    a1 += wA * bf2f(uA.y) + wB * bf2f(uB.y) + wC * bf2f(uC.y) + wD * bf2f(uD.y);
    a2 += wA * bf2f(uA.z) + wB * bf2f(uB.z) + wC * bf2f(uC.z) + wD * bf2f(uD.z);
    a3 += wA * bf2f(uA.w) + wB * bf2f(uB.w) + wC * bf2f(uC.w) + wD * bf2f(uD.w);
  }
  if (idx + 4 <= end) {
    int2 rA = spk[idx + half];
    int2 rB = spk[idx + 2 + half];
    float wA = __int_as_float(rA.y), wB = __int_as_float(rB.y);
    ushort4 uA = *(const ushort4*)&XWb[(long long)rA.x * 128 + fl];
    ushort4 uB = *(const ushort4*)&XWb[(long long)rB.x * 128 + fl];
    a0 += wA * bf2f(uA.x) + wB * bf2f(uB.x);
    a1 += wA * bf2f(uA.y) + wB * bf2f(uB.y);
    a2 += wA * bf2f(uA.z) + wB * bf2f(uB.z);
    a3 += wA * bf2f(uA.w) + wB * bf2f(uB.w);
    idx += 4;
  }
  if (idx < end) {
    int iA = idx + half;
    int2 rA = spk[min(iA, end - 1)];
    float wA = (iA < end) ? __int_as_float(rA.y) : 0.f;
    ushort4 uA = *(const ushort4*)&XWb[(long long)rA.x * 128 + fl];
    a0 += wA * bf2f(uA.x); a1 += wA * bf2f(uA.y);
    a2 += wA * bf2f(uA.z); a3 += wA * bf2f(uA.w);
    if (idx + 2 < end) {
      int iB = idx + 2 + half;
      int2 rB = spk[min(iB, end - 1)];
      float wB = (iB < end) ? __int_as_float(rB.y) : 0.f;
      ushort4 uB = *(const ushort4*)&XWb[(long long)rB.x * 128 + fl];
      a0 += wB * bf2f(uB.x); a1 += wB * bf2f(uB.y);
      a2 += wB * bf2f(uB.z); a3 += wB * bf2f(uB.w);
    }
  }
  a0 += __shfl_xor(a0, 32, 64);
  a1 += __shfl_xor(a1, 32, 64);
  a2 += __shfl_xor(a2, 32, 64);
  a3 += __shfl_xor(a3, 32, 64);
  if (half == 0) {
    ushort4 su = *(const ushort4*)&XWb[(long long)wid * 128 + fl];
    float d2 = di * di;
    float o0 = di * a0 + d2 * bf2f(su.x);
    float o1 = di * a1 + d2 * bf2f(su.y);
    float o2 = di * a2 + d2 * bf2f(su.z);
    float o3 = di * a3 + d2 * bf2f(su.w);
    if (bias_fi >= 0) {
      if (flags[bias_fi]) {
        float4 bv = *(const float4*)&((const float*)bias_raw)[fl];
        o0 += bv.x; o1 += bv.y; o2 += bv.z; o3 += bv.w;
      } else {
        const unsigned short* bu = (const unsigned short*)bias_raw;
        o0 += bf2f(bu[fl]); o1 += bf2f(bu[fl + 1]);
        o2 += bf2f(bu[fl + 2]); o3 += bf2f(bu[fl + 3]);
      }
    }
    if (relu) {
      o0 = fmaxf(o0, 0.f); o1 = fmaxf(o1, 0.f);
      o2 = fmaxf(o2, 0.f); o3 = fmaxf(o3, 0.f);
    }
    if (out_bf16) {     // gemm2 converts to bf16 anyway: numerically identical
      ushort4 uo;
      uo.x = f2bf(o0); uo.y = f2bf(o1); uo.z = f2bf(o2); uo.w = f2bf(o3);
      *(ushort4*)&((unsigned short*)H)[(long long)wid * 128 + fl] = uo;
    } else {
      *(float4*)&((float*)H)[(long long)wid * 128 + fl] = make_float4(o0, o1, o2, o3);
    }
  }
}

// ---------- 5a. pool phase A ----------
__global__ __launch_bounds__(256) void pool_partial_k(const float* __restrict__ H,
    const int* __restrict__ batch, float* __restrict__ acc, int N,
    const int* __restrict__ flags) {
  const int i64 = flags[1];
  const int lane = threadIdx.x & 63;
  const int w = threadIdx.x >> 6;
  const int chunk = (N + gridDim.x - 1) / gridDim.x;
  const int bstart = blockIdx.x * chunk;
  const int bend = min(bstart + chunk, N);
  const int sub = (chunk + 3) / 4;
  const int s = bstart + w * sub;
  const int e = min(s + sub, bend);
  if (s >= e) return;
  float ax = 0.f, ay = 0.f;
  int curg = i64 ? batch[2 * s] : batch[s];
  for (int n = s; n < e; ++n) {
    int g = i64 ? batch[2 * n] : batch[n];
    if (g != curg) {
      atomicAdd(&acc[curg * 128 + lane * 2], ax);
      atomicAdd(&acc[curg * 128 + lane * 2 + 1], ay);
      ax = ay = 0.f; curg = g;
    }
    float2 v = *(const float2*)&H[(long long)n * 128 + lane * 2];
    ax += v.x; ay += v.y;
  }
  atomicAdd(&acc[curg * 128 + lane * 2], ax);
  atomicAdd(&acc[curg * 128 + lane * 2 + 1], ay);
}

// ---------- 5b. pool finalize ----------
__global__ __launch_bounds__(128) void pool_final_k(const float* __restrict__ acc,
    const int* __restrict__ batch, const void* __restrict__ B2raw,
    float* __restrict__ out, int N, const int* __restrict__ flags) {
  __shared__ int sb[2];
  int g = blockIdx.x;
  int i64 = flags[1];
  if (threadIdx.x < 2) {
    int target = g + threadIdx.x;
    int lo = 0, hi = N;
    while (lo < hi) {
      int mid = (lo + hi) >> 1;
      int bv = i64 ? batch[2 * mid] : batch[mid];
      if (bv < target) lo = mid + 1; else hi = mid;
    }
    sb[threadIdx.x] = lo;
  }
  __syncthreads();
  int cnt = sb[1] - sb[0];
  int f = threadIdx.x;
  float b2 = flags[5] ? ((const float*)B2raw)[f]
                      : bf2f(((const unsigned short*)B2raw)[f]);
  float res = 0.f;
  if (cnt > 0) res = acc[g * 128 + f] / (float)cnt + b2;
  out[g * 128 + f] = res;
}

extern "C" void kernel_launch(void* const* d_in, const int* in_sizes, int n_in,
                              void* d_out, int out_size, void* d_ws, size_t ws_size,
                              hipStream_t stream) {
  const int N = in_sizes[0] / 128;   // 50000
  const int E = in_sizes[1] / 2;     // 800000
  const int G = out_size / 128;      // 64
  const int NB = (N + 255) >> SPAN_SHIFT;  // dst buckets (196), <=256
  const int GB = (N + 63) / 64;            // gemm blocks
  const int SA = (E + 4095) / 4096;        // scatterA blocks
  const int ZB = (NB + G * 128 + 4095) / 4096;  // zeroing blocks

  const void* X  = d_in[0];
  const int*  EI = (const int*)d_in[1];
  const int*  BA = (const int*)d_in[2];
  const void* W1 = d_in[3];
  const void* B1 = d_in[4];
  const void* W2 = d_in[5];
  const void* B2 = d_in[6];
  float* OUT = (float*)d_out;

  char* ws = (char*)d_ws;
  size_t o = 0;
  auto alloc = [&](size_t b) { size_t r = o; o += (b + 255) & ~(size_t)255; return r; };
  int*   flags  = (int*)(ws + alloc(256));
  unsigned short* w1s = (unsigned short*)(ws + alloc(16384 * 2));  // pre-swizzled bf16
  unsigned short* w2s = (unsigned short*)(ws + alloc(16384 * 2));
  float* acc    = (float*)(ws + alloc((size_t)G * 128 * 4));
  int*   bcnt   = (int*)(ws + alloc(256 * 4));
  int*   rowptr = (int*)(ws + alloc((size_t)(N + 1) * 4));
  int2*  spk    = (int2*)(ws + alloc((size_t)E * 8));
  float* dinv   = (float*)(ws + alloc((size_t)N * 4));
  unsigned short* xwb = (unsigned short*)(ws + alloc((size_t)N * 128 * 2));
  char*  hreg   = ws + alloc((size_t)N * 128 * 4);  // 25.6 MB multi-use region
  unsigned short* h1b = (unsigned short*)hreg;      // layer-1 H, bf16 (12.8 MB)
  float* h2f    = (float*)hreg;                     // layer-2 H, fp32 (25.6 MB)
  int2*  tmp    = (int2*)hreg;                      // bucket regions 12.85 MB; dead before aggregate1

  // 1. probes + W pre-swizzle + zeroing (one launch)
  detect_swz_zero_k<<<132 + ZB, 256, 0, stream>>>(
      (const unsigned short*)X, EI,
      (const unsigned short*)B1, (const unsigned short*)B2,
      W1, W2, w1s, w2s, flags, bcnt, acc, NB, G * 128);
  // 2. fused scatterA + gemm1
  scatA_gemm1_k<<<SA + GB, 256, 0, stream>>>(EI, bcnt, tmp, E, SA,
                                             X, w1s, xwb, N, flags, NB);
  // 3. CSR finish
  scatB1_k<<<NB, 256, 0, stream>>>(tmp, bcnt, rowptr, dinv, N, NB, E);
  scatB2_k<<<NB, 256, 0, stream>>>(tmp, bcnt, rowptr, dinv, spk, N);

  dim3 agrid((N * 64 + 255) / 256);
  // layer 1 aggregate (bf16 out; tmp is dead now)
  aggregate_k<<<agrid, 256, 0, stream>>>(xwb, rowptr, spk, dinv, B1, 4,
                                         h1b, N, 1, 1, flags);
  // layer 2
  gemm_k<<<GB, 256, 0, stream>>>(h1b, w2s, xwb, N, 2);
  aggregate_k<<<agrid, 256, 0, stream>>>(xwb, rowptr, spk, dinv, (const void*)nullptr, -1,
                                         h2f, N, 0, 0, flags);
  // pool
  pool_partial_k<<<512, 256, 0, stream>>>(h2f, BA, acc, N, flags);
  pool_final_k<<<G, 128, 0, stream>>>(acc, BA, B2, OUT, N, flags);
}

// Round 14
// 219.795 us; speedup vs baseline: 1.4671x; 1.0458x over previous
//
#include <hip/hip_runtime.h>
#include <hip/hip_bf16.h>

#define SPAN_SHIFT 8      // dst-bucket span = 256 nodes
#define BCAP 8192         // per-bucket tmp capacity (mean ~4080, >60 sigma safety)

typedef __attribute__((ext_vector_type(8))) short short8;
typedef __attribute__((ext_vector_type(4))) float float4v;

// ---------- bf16 helpers (OCP bf16 = fp32 upper 16 bits) ----------
__device__ __forceinline__ float bf2f(unsigned short u) {
  union { unsigned int i; float f; } v; v.i = ((unsigned int)u) << 16; return v.f;
}
__device__ __forceinline__ unsigned short f2bf(float f) {
  union { float f; unsigned int i; } v; v.f = f;
  unsigned int x = v.i;
  return (unsigned short)((x + 0x7fffu + ((x >> 16) & 1u)) >> 16);  // RNE
}

// ---------- 0. dtype probes + W pre-swizzle (self-probed) + zero bcnt/acc ----------
// flags[0]=x_fp32 flags[1]=int64 flags[4]=b1_fp32 flags[5]=b2_fp32
// blocks: 0..3 probes, 4..131 swizzle (W1:4..67, W2:68..131), 132.. zeroing
__global__ __launch_bounds__(256) void detect_swz_zero_k(
    const unsigned short* __restrict__ xu,  const int* __restrict__ ei,
    const unsigned short* __restrict__ b1u, const unsigned short* __restrict__ b2u,
    const void* __restrict__ W1, const void* __restrict__ W2,
    unsigned short* __restrict__ w1s, unsigned short* __restrict__ w2s,
    int* __restrict__ flags, int* __restrict__ bcnt, float* __restrict__ acc,
    int NBKT, int GP) {
  const int b = blockIdx.x;
  const int tid = threadIdx.x;
  if (b >= 132) {                                 // zeroing blocks
    int base = (b - 132) * 4096 + tid;
    #pragma unroll
    for (int j = 0; j < 16; ++j) {
      int i = base + j * 256;
      if (i < NBKT) bcnt[i] = 0;
      else if (i < NBKT + GP) acc[i - NBKT] = 0.f;
    }
    return;
  }
  __shared__ int s_cnt;
  if (tid == 0) s_cnt = 0;
  __syncthreads();
  if (b >= 4) {                                   // swizzle blocks, self-probe W dtype
    const void* Wraw = (b < 68) ? W1 : W2;
    unsigned short* out = (b < 68) ? w1s : w2s;
    const unsigned short* Wu = (const unsigned short*)Wraw;
    int c = 0;
    for (int i = tid; i < 512; i += 256) {
      int e = (Wu[i] >> 7) & 0xFF;
      if (e < 96 || e > 159) c++;                 // fp32 halves look wild as bf16
    }
    atomicAdd(&s_cnt, c);
    __syncthreads();
    const int wf32 = s_cnt > 64;
    int u = ((b - 4) & 63) * 256 + tid;           // 0..16383
    int j = u & 7, lane = (u >> 3) & 63, blk = u >> 9;
    int cc = blk >> 3, t = blk & 7;
    int quad = lane >> 4, col = lane & 15;
    int k = cc * 32 + quad * 8 + j;
    int n = t * 16 + col;
    out[u] = wf32 ? f2bf(((const float*)Wraw)[k * 128 + n])
                  : ((const unsigned short*)Wraw)[k * 128 + n];
    return;
  }
  int cnt = 0;
  if (b == 1) {  // int width: high words of int64 positives are all zero
    for (int i = tid; i < 4096; i += 256)
      if (ei[2 * i + 1] == 0) cnt++;
    atomicAdd(&s_cnt, cnt);
    __syncthreads();
    if (tid == 0) flags[1] = (s_cnt > 2048) ? 1 : 0;
    return;
  }
  const unsigned short* p; int n; int fi;
  if (b == 0)      { p = xu;  n = 16384; fi = 0; }
  else if (b == 2) { p = b1u; n = 128;   fi = 4; }
  else             { p = b2u; n = 128;   fi = 5; }
  for (int i = tid; i < n; i += 256) {
    int e = (p[i] >> 7) & 0xFF;
    if (e < 96 || e > 159) cnt++;
  }
  atomicAdd(&s_cnt, cnt);
  __syncthreads();
  if (tid == 0) flags[fi] = (s_cnt * 8 > n) ? 1 : 0;
}

// ---------- shared GEMM body (W pre-swizzled; LDS-staged coalesced C-store) ----------
__device__ __forceinline__ void gemm_body(const void* __restrict__ X,
                                          const unsigned short* __restrict__ Wsw,
                                          unsigned short* __restrict__ XWb, int N,
                                          int xf32, int row0,
                                          unsigned short* Wl, unsigned short* Xl) {
  const int tid = threadIdx.x;
  for (int v = tid; v < 2048; v += 256)           // W: linear conflict-free copy
    ((short8*)Wl)[v] = ((const short8*)Wsw)[v];
  for (int v = tid; v < 2048; v += 256) {         // X: 64 rows x 128, bf16, pad +8
    int r = v >> 5, k4 = (v & 31) * 4;
    int row = row0 + r;
    ushort4 u = make_ushort4(0, 0, 0, 0);
    if (row < N) {
      long long gi = (long long)row * 128 + k4;
      if (xf32) {
        float4 xv = *(const float4*)&((const float*)X)[gi];
        u.x = f2bf(xv.x); u.y = f2bf(xv.y); u.z = f2bf(xv.z); u.w = f2bf(xv.w);
      } else {
        u = *(const ushort4*)&((const unsigned short*)X)[gi];
      }
    }
    *(ushort4*)&Xl[r * 136 + k4] = u;
  }
  __syncthreads();
  const int w = tid >> 6, lane = tid & 63;
  const int quad = lane >> 4, col = lane & 15;
  float4v acc[8];
  #pragma unroll
  for (int t = 0; t < 8; ++t) acc[t] = (float4v){0.f, 0.f, 0.f, 0.f};
  #pragma unroll
  for (int c = 0; c < 4; ++c) {
    short8 a = *(const short8*)&Xl[(w * 16 + col) * 136 + c * 32 + quad * 8];
    #pragma unroll
    for (int t = 0; t < 8; ++t) {
      short8 b = *(const short8*)&Wl[((c * 8 + t) * 64 + lane) * 8];
      acc[t] = __builtin_amdgcn_mfma_f32_16x16x32_bf16(a, b, acc[t], 0, 0, 0);
    }
  }
  // C-store via own 16-row LDS region, then coalesced 16-B copy-out
  #pragma unroll
  for (int t = 0; t < 8; ++t) {
    #pragma unroll
    for (int r = 0; r < 4; ++r)
      Xl[(w * 16 + quad * 4 + r) * 136 + t * 16 + col] = f2bf(acc[t][r]);
  }
  __syncthreads();
  for (int v = tid; v < 1024; v += 256) {
    int r = v >> 4, ck = (v & 15) * 8;
    int row = row0 + r;
    if (row < N)
      *(short8*)&XWb[(long long)row * 128 + ck] = *(const short8*)&Xl[r * 136 + ck];
  }
}

// ---------- 1. fused: scatterA (blocks < SA) + gemm1 (blocks >= SA) ----------
__global__ __launch_bounds__(256) void scatA_gemm1_k(const int* __restrict__ ei,
    int* __restrict__ bcnt, int2* __restrict__ tmp, int E, int SA,
    const void* __restrict__ X, const unsigned short* __restrict__ Wsw,
    unsigned short* __restrict__ XWb, int N,
    const int* __restrict__ flags, int NBKT) {
  __shared__ __align__(16) char smem[50688];
  const int tid = threadIdx.x;
  if ((int)blockIdx.x >= SA) {                    // gemm1 blocks
    unsigned short* Wl = (unsigned short*)smem;           // 32 KB
    unsigned short* Xl = (unsigned short*)(smem + 32768); // 17.4 KB
    gemm_body(X, Wsw, XWb, N, flags[0], ((int)blockIdx.x - SA) * 64, Wl, Xl);
    return;
  }
  // ---- scatterA body ----
  int2* stage = (int2*)smem;                      // 32 KB
  int* hist  = (int*)(smem + 32768);
  int* off   = hist + 256;
  int* cnt2  = off + 256;
  int* gbase = cnt2 + 256;
  int* wsum  = gbase + 256;
  hist[tid] = 0; cnt2[tid] = 0;
  __syncthreads();
  const int base = blockIdx.x * 4096;
  const int i64 = flags[1];
  int rs[16], rd[16];
  #pragma unroll
  for (int j = 0; j < 16; ++j) {
    int e = base + j * 256 + tid;
    if (e < E) {
      int s, d;
      if (i64) { s = ei[2 * e]; d = ei[2 * (E + e)]; }
      else     { s = ei[e];     d = ei[E + e]; }
      rs[j] = s; rd[j] = d;
      atomicAdd(&hist[d >> SPAN_SHIFT], 1);
    } else rd[j] = -1;
  }
  __syncthreads();
  {
    int lane = tid & 63, w = tid >> 6;
    int v = hist[tid], inc = v;
    #pragma unroll
    for (int o = 1; o < 64; o <<= 1) { int n = __shfl_up(inc, o, 64); if (lane >= o) inc += n; }
    if (lane == 63) wsum[w] = inc;
    __syncthreads();
    int pre = 0;
    #pragma unroll
    for (int k = 0; k < 4; ++k) if (k < w) pre += wsum[k];
    off[tid] = pre + inc - v;
  }
  __syncthreads();
  #pragma unroll
  for (int j = 0; j < 16; ++j) {
    if (rd[j] >= 0) {
      int b = rd[j] >> SPAN_SHIFT;
      int r = atomicAdd(&cnt2[b], 1);
      int2 rec; rec.x = rs[j]; rec.y = rd[j];
      stage[off[b] + r] = rec;
    }
  }
  if (tid < NBKT && hist[tid] > 0)
    gbase[tid] = tid * BCAP + atomicAdd(&bcnt[tid], hist[tid]);
  __syncthreads();
  const int total = off[255] + hist[255];
  for (int i = tid; i < total; i += 256) {
    int2 rec = stage[i];
    int b = rec.y >> SPAN_SHIFT;
    tmp[gbase[b] + (i - off[b])] = rec;
  }
}

// ---------- generic GEMM (xmode: 1 = fp32 input, 2 = bf16 input) ----------
__global__ __launch_bounds__(256) void gemm_k(const void* __restrict__ X,
                                              const unsigned short* __restrict__ Wsw,
                                              unsigned short* __restrict__ XWb, int N,
                                              int xmode) {
  __shared__ __align__(16) unsigned short Wl[16384];
  __shared__ __align__(16) unsigned short Xl[64 * 136];
  gemm_body(X, Wsw, XWb, N, (xmode == 1) ? 1 : 0, blockIdx.x * 64, Xl ? Wl : Wl, Xl);
}

// ---------- 2. scatB: hist -> rowptr+dinv -> place (one kernel, src-only spk) ----------
__global__ __launch_bounds__(256) void scatB_k(const int2* __restrict__ tmp,
    const int* __restrict__ bcnt, int* __restrict__ rowptr,
    float* __restrict__ dinv, int* __restrict__ spk, int N, int NBKT, int E) {
  __shared__ int hist[256];
  __shared__ int pfx[256];
  __shared__ int cur[256];
  __shared__ int ws[4];
  const int tid = threadIdx.x;
  const int b = blockIdx.x;
  const int lane = tid & 63, w = tid >> 6;
  // global prefix over bucket counts (196 ints, L2-hot; every block computes it)
  int c = (tid < NBKT) ? bcnt[tid] : 0;
  hist[tid] = 0;
  {
    int inc = c;
    #pragma unroll
    for (int o = 1; o < 64; o <<= 1) { int n = __shfl_up(inc, o, 64); if (lane >= o) inc += n; }
    if (lane == 63) ws[w] = inc;
    __syncthreads();
    int pre = 0;
    #pragma unroll
    for (int k = 0; k < 4; ++k) if (k < w) pre += ws[k];
    pfx[tid] = pre + inc - c;
  }
  __syncthreads();
  const int bbase = pfx[b];
  const int cnt = bcnt[b];
  const int2* src = tmp + (long long)b * BCAP;
  for (int i = tid; i < cnt; i += 256)
    atomicAdd(&hist[src[i].y & 255], 1);
  __syncthreads();
  int v = hist[tid], inc = v;
  #pragma unroll
  for (int o = 1; o < 64; o <<= 1) {
    int n = __shfl_up(inc, o, 64);
    if (lane >= o) inc += n;
  }
  if (lane == 63) ws[w] = inc;
  __syncthreads();
  int pre = 0;
  #pragma unroll
  for (int k = 0; k < 4; ++k) if (k < w) pre += ws[k];
  const int start = bbase + pre + inc - v;
  int node = (b << SPAN_SHIFT) + tid;
  if (node < N) {
    rowptr[node] = start;
    dinv[node] = rsqrtf((float)(v + 1));   // +1 self-loop
  }
  cur[tid] = start;
  if (b == 0 && tid == 0) rowptr[N] = E;
  __syncthreads();
  for (int i = tid; i < cnt; i += 256) {   // place (src-only payload)
    int2 rec = src[i];
    int pos = atomicAdd(&cur[rec.y & 255], 1);
    spk[pos] = rec.x;
  }
}

// ---------- 3. aggregate: quarter-wave, 16-B gathers, 16 edges in flight ----------
// Lane owns 8 features (short8 = 16 B); 16 lanes cover a 256-B row; the wave's
// 4 quarters gather 4 different edges per instruction (1 KB/instruction).
__global__ __launch_bounds__(256) void aggregate_k(const unsigned short* __restrict__ XWb,
    const int* __restrict__ rowptr, const int* __restrict__ spk,
    const float* __restrict__ dinv, const void* __restrict__ bias_raw, int bias_fi,
    void* __restrict__ H, int N, int relu, int out_bf16,
    const int* __restrict__ flags) {
  int wid = (blockIdx.x * 256 + threadIdx.x) >> 6;  // one wave per node
  if (wid >= N) return;
  const int lane = threadIdx.x & 63;
  const int q = lane >> 4;           // quarter: which edge of the group
  const int fl = (lane & 15) * 8;    // 8 features per lane
  const int beg = rowptr[wid], end = rowptr[wid + 1];
  const float di = dinv[wid];
  float a[8];
  #pragma unroll
  for (int j = 0; j < 8; ++j) a[j] = 0.f;
  int idx = beg;
  for (; idx + 16 <= end; idx += 16) {
    int s0 = spk[idx + q];
    int s1 = spk[idx + 4 + q];
    int s2 = spk[idx + 8 + q];
    int s3 = spk[idx + 12 + q];
    float w0 = dinv[s0], w1 = dinv[s1], w2 = dinv[s2], w3 = dinv[s3];
    short8 u0 = *(const short8*)&XWb[(long long)s0 * 128 + fl];
    short8 u1 = *(const short8*)&XWb[(long long)s1 * 128 + fl];
    short8 u2 = *(const short8*)&XWb[(long long)s2 * 128 + fl];
    short8 u3 = *(const short8*)&XWb[(long long)s3 * 128 + fl];
    #pragma unroll
    for (int j = 0; j < 8; ++j)
      a[j] += w0 * bf2f((unsigned short)u0[j]) + w1 * bf2f((unsigned short)u1[j])
            + w2 * bf2f((unsigned short)u2[j]) + w3 * bf2f((unsigned short)u3[j]);
  }
  if (idx + 8 <= end) {
    int s0 = spk[idx + q];
    int s1 = spk[idx + 4 + q];
    float w0 = dinv[s0], w1 = dinv[s1];
    short8 u0 = *(const short8*)&XWb[(long long)s0 * 128 + fl];
    short8 u1 = *(const short8*)&XWb[(long long)s1 * 128 + fl];
    #pragma unroll
    for (int j = 0; j < 8; ++j)
      a[j] += w0 * bf2f((unsigned short)u0[j]) + w1 * bf2f((unsigned short)u1[j]);
    idx += 8;
  }
  if (idx + 4 <= end) {
    int s0 = spk[idx + q];
    float w0 = dinv[s0];
    short8 u0 = *(const short8*)&XWb[(long long)s0 * 128 + fl];
    #pragma unroll
    for (int j = 0; j < 8; ++j)
      a[j] += w0 * bf2f((unsigned short)u0[j]);
    idx += 4;
  }
  if (idx < end) {                    // 1..3 edges: clamp, zero-weight invalid
    int e = idx + q;
    int s0 = spk[min(e, end - 1)];
    float w0 = (e < end) ? dinv[s0] : 0.f;
    short8 u0 = *(const short8*)&XWb[(long long)s0 * 128 + fl];
    #pragma unroll
    for (int j = 0; j < 8; ++j)
      a[j] += w0 * bf2f((unsigned short)u0[j]);
  }
  #pragma unroll
  for (int j = 0; j < 8; ++j) {       // cross-quarter reduce
    a[j] += __shfl_xor(a[j], 16, 64);
    a[j] += __shfl_xor(a[j], 32, 64);
  }
  if (q == 0) {
    short8 su = *(const short8*)&XWb[(long long)wid * 128 + fl];
    float d2 = di * di;
    float o[8];
    #pragma unroll
    for (int j = 0; j < 8; ++j)
      o[j] = di * a[j] + d2 * bf2f((unsigned short)su[j]);
    if (bias_fi >= 0) {
      if (flags[bias_fi]) {
        const float* bf = (const float*)bias_raw;
        float4 b0 = *(const float4*)&bf[fl];
        float4 b1 = *(const float4*)&bf[fl + 4];
        o[0] += b0.x; o[1] += b0.y; o[2] += b0.z; o[3] += b0.w;
        o[4] += b1.x; o[5] += b1.y; o[6] += b1.z; o[7] += b1.w;
      } else {
        const unsigned short* bu = (const unsigned short*)bias_raw;
        #pragma unroll
        for (int j = 0; j < 8; ++j) o[j] += bf2f(bu[fl + j]);
      }
    }
    if (relu) {
      #pragma unroll
      for (int j = 0; j < 8; ++j) o[j] = fmaxf(o[j], 0.f);
    }
    if (out_bf16) {
      short8 uo;
      #pragma unroll
      for (int j = 0; j < 8; ++j) uo[j] = (short)f2bf(o[j]);
      *(short8*)&((unsigned short*)H)[(long long)wid * 128 + fl] = uo;
    } else {
      float* Hf = (float*)H;
      *(float4*)&Hf[(long long)wid * 128 + fl]     = make_float4(o[0], o[1], o[2], o[3]);
      *(float4*)&Hf[(long long)wid * 128 + fl + 4] = make_float4(o[4], o[5], o[6], o[7]);
    }
  }
}

// ---------- 4a. pool phase A ----------
__global__ __launch_bounds__(256) void pool_partial_k(const float* __restrict__ H,
    const int* __restrict__ batch, float* __restrict__ acc, int N,
    const int* __restrict__ flags) {
  const int i64 = flags[1];
  const int lane = threadIdx.x & 63;
  const int w = threadIdx.x >> 6;
  const int chunk = (N + gridDim.x - 1) / gridDim.x;
  const int bstart = blockIdx.x * chunk;
  const int bend = min(bstart + chunk, N);
  const int sub = (chunk + 3) / 4;
  const int s = bstart + w * sub;
  const int e = min(s + sub, bend);
  if (s >= e) return;
  float ax = 0.f, ay = 0.f;
  int curg = i64 ? batch[2 * s] : batch[s];
  for (int n = s; n < e; ++n) {
    int g = i64 ? batch[2 * n] : batch[n];
    if (g != curg) {
      atomicAdd(&acc[curg * 128 + lane * 2], ax);
      atomicAdd(&acc[curg * 128 + lane * 2 + 1], ay);
      ax = ay = 0.f; curg = g;
    }
    float2 v = *(const float2*)&H[(long long)n * 128 + lane * 2];
    ax += v.x; ay += v.y;
  }
  atomicAdd(&acc[curg * 128 + lane * 2], ax);
  atomicAdd(&acc[curg * 128 + lane * 2 + 1], ay);
}

// ---------- 4b. pool finalize ----------
__global__ __launch_bounds__(128) void pool_final_k(const float* __restrict__ acc,
    const int* __restrict__ batch, const void* __restrict__ B2raw,
    float* __restrict__ out, int N, const int* __restrict__ flags) {
  __shared__ int sb[2];
  int g = blockIdx.x;
  int i64 = flags[1];
  if (threadIdx.x < 2) {
    int target = g + threadIdx.x;
    int lo = 0, hi = N;
    while (lo < hi) {
      int mid = (lo + hi) >> 1;
      int bv = i64 ? batch[2 * mid] : batch[mid];
      if (bv < target) lo = mid + 1; else hi = mid;
    }
    sb[threadIdx.x] = lo;
  }
  __syncthreads();
  int cnt = sb[1] - sb[0];
  int f = threadIdx.x;
  float b2 = flags[5] ? ((const float*)B2raw)[f]
                      : bf2f(((const unsigned short*)B2raw)[f]);
  float res = 0.f;
  if (cnt > 0) res = acc[g * 128 + f] / (float)cnt + b2;
  out[g * 128 + f] = res;
}

extern "C" void kernel_launch(void* const* d_in, const int* in_sizes, int n_in,
                              void* d_out, int out_size, void* d_ws, size_t ws_size,
                              hipStream_t stream) {
  const int N = in_sizes[0] / 128;   // 50000
  const int E = in_sizes[1] / 2;     // 800000
  const int G = out_size / 128;      // 64
  const int NB = (N + 255) >> SPAN_SHIFT;  // dst buckets (196), <=256
  const int GB = (N + 63) / 64;            // gemm blocks
  const int SA = (E + 4095) / 4096;        // scatterA blocks
  const int ZB = (NB + G * 128 + 4095) / 4096;  // zeroing blocks

  const void* X  = d_in[0];
  const int*  EI = (const int*)d_in[1];
  const int*  BA = (const int*)d_in[2];
  const void* W1 = d_in[3];
  const void* B1 = d_in[4];
  const void* W2 = d_in[5];
  const void* B2 = d_in[6];
  float* OUT = (float*)d_out;

  char* ws = (char*)d_ws;
  size_t o = 0;
  auto alloc = [&](size_t b) { size_t r = o; o += (b + 255) & ~(size_t)255; return r; };
  int*   flags  = (int*)(ws + alloc(256));
  unsigned short* w1s = (unsigned short*)(ws + alloc(16384 * 2));  // pre-swizzled bf16
  unsigned short* w2s = (unsigned short*)(ws + alloc(16384 * 2));
  float* acc    = (float*)(ws + alloc((size_t)G * 128 * 4));
  int*   bcnt   = (int*)(ws + alloc(256 * 4));
  int*   rowptr = (int*)(ws + alloc((size_t)(N + 1) * 4));
  int*   spk    = (int*)(ws + alloc((size_t)E * 4));      // src-only payload
  float* dinv   = (float*)(ws + alloc((size_t)N * 4));
  unsigned short* xwb = (unsigned short*)(ws + alloc((size_t)N * 128 * 2));
  char*  hreg   = ws + alloc((size_t)N * 128 * 4);  // 25.6 MB multi-use region
  unsigned short* h1b = (unsigned short*)hreg;      // layer-1 H, bf16 (12.8 MB)
  float* h2f    = (float*)hreg;                     // layer-2 H, fp32 (25.6 MB)
  int2*  tmp    = (int2*)hreg;                      // bucket regions 12.85 MB; dead before aggregate1

  // 1. probes + W pre-swizzle + zeroing (one launch)
  detect_swz_zero_k<<<132 + ZB, 256, 0, stream>>>(
      (const unsigned short*)X, EI,
      (const unsigned short*)B1, (const unsigned short*)B2,
      W1, W2, w1s, w2s, flags, bcnt, acc, NB, G * 128);
  // 2. fused scatterA + gemm1
  scatA_gemm1_k<<<SA + GB, 256, 0, stream>>>(EI, bcnt, tmp, E, SA,
                                             X, w1s, xwb, N, flags, NB);
  // 3. CSR finish (single merged kernel)
  scatB_k<<<NB, 256, 0, stream>>>(tmp, bcnt, rowptr, dinv, spk, N, NB, E);

  dim3 agrid((N * 64 + 255) / 256);
  // layer 1 aggregate (bf16 out; tmp is dead now)
  aggregate_k<<<agrid, 256, 0, stream>>>(xwb, rowptr, spk, dinv, B1, 4,
                                         h1b, N, 1, 1, flags);
  // layer 2
  gemm_k<<<GB, 256, 0, stream>>>(h1b, w2s, xwb, N, 2);
  aggregate_k<<<agrid, 256, 0, stream>>>(xwb, rowptr, spk, dinv, (const void*)nullptr, -1,
                                         h2f, N, 0, 0, flags);
  // pool
  pool_partial_k<<<512, 256, 0, stream>>>(h2f, BA, acc, N, flags);
  pool_final_k<<<G, 128, 0, stream>>>(acc, BA, B2, OUT, N, flags);
}